// Round 5
// baseline (13269.304 us; speedup 1.0000x reference)
//
#include <hip/hip_runtime.h>

typedef unsigned short ushort_t;
typedef __attribute__((ext_vector_type(4))) float f32x4;
typedef __attribute__((ext_vector_type(8))) short s16x8;
typedef __attribute__((ext_vector_type(4))) unsigned short u16x4;
typedef __attribute__((ext_vector_type(8))) __bf16 bf16x8;

#define DEV __device__ __forceinline__

DEV float bf2f(ushort_t u){ union { unsigned int i; float f; } v; v.i = ((unsigned int)u) << 16; return v.f; }
DEV ushort_t f2bf(float f){
  union { float f; unsigned int i; } v; v.f = f;
  unsigned int r = v.i + 0x7FFFu + ((v.i >> 16) & 1u);   // RNE
  return (ushort_t)(r >> 16);
}
DEV float frcp(float x){
#if __has_builtin(__builtin_amdgcn_rcpf)
  return __builtin_amdgcn_rcpf(x);
#else
  return 1.0f / x;
#endif
}
DEV float fast_tanh(float x){
  x = fminf(9.0f, fmaxf(-9.0f, x));
  float e = __expf(2.0f * x);
  return fmaf(-2.0f, frcp(e + 1.0f), 1.0f);
}
DEV float fast_sig(float x){ return frcp(1.0f + __expf(-x)); }

DEV f32x4 mfma16(s16x8 a, s16x8 b, f32x4 c){
  return __builtin_amdgcn_mfma_f32_16x16x32_bf16(
      __builtin_bit_cast(bf16x8, a), __builtin_bit_cast(bf16x8, b), c, 0, 0, 0);
}

// Hierarchical device barrier over 256 blocks (fresh slots per use).
// Group g (=bid&7, ~XCD): 32 adds on group ctr; 32nd adds root; 8th root
// releases 8 flags; everyone spins their group flag. Agent-scope acq_rel
// atomics carry the happens-before chain for prior plain stores.
DEV void dbar(unsigned* inst, int g){
  __syncthreads();
  if (threadIdx.x == 0) {
    unsigned old = __hip_atomic_fetch_add(inst + g * 16, 1u, __ATOMIC_ACQ_REL, __HIP_MEMORY_SCOPE_AGENT);
    if (old == 31u) {
      unsigned ro = __hip_atomic_fetch_add(inst + 128, 1u, __ATOMIC_ACQ_REL, __HIP_MEMORY_SCOPE_AGENT);
      if (ro == 7u) {
        #pragma unroll
        for (int i = 0; i < 8; ++i)
          __hip_atomic_store(inst + 160 + i * 8, 1u, __ATOMIC_RELEASE, __HIP_MEMORY_SCOPE_AGENT);
      }
    }
    while (__hip_atomic_load(inst + 160 + g * 8, __ATOMIC_ACQUIRE, __HIP_MEMORY_SCOPE_AGENT) == 0u)
      __builtin_amdgcn_s_sleep(2);
  }
  __syncthreads();
}

// ---------------------------------------------------------------------------
// One-shot GEMMs: C[m,n] = sum_k A[m,k]*B[n,k].
// MODE 0: A=h f32, B=W_attn2 f32 -> z2 bf16 (+b_attn1[n]+b_attn2[n])
// MODE 2: A=dct bf16 [256,2048], B=W_fc1 f32 [1024,2048] -> f32 [256,1024]
// ---------------------------------------------------------------------------
template<int MODE>
__global__ __launch_bounds__(256) void gemm_bt_k(
    const void* __restrict__ Ap, const void* __restrict__ Bp,
    void* __restrict__ Cp, const float* __restrict__ bias1, const float* __restrict__ bias2)
{
  const int bm0 = blockIdx.x * 64;
  const int bn0 = blockIdx.y * 64;
  const int tid = threadIdx.x;
  const int srow = tid >> 2, sseg = tid & 3;
  const int wid = tid >> 6, lane = tid & 63;
  const int wr = wid >> 1, wc = wid & 1;
  const int fr = lane & 15, kseg = lane >> 4;

  int K;
  const float* Af = nullptr; const ushort_t* Ab = nullptr;
  const float* Bf = nullptr;
  if constexpr (MODE == 0) {
    K = 1024;
    Af = (const float*)Ap + (size_t)(bm0 + srow) * 1024;
    Bf = (const float*)Bp + (size_t)(bn0 + srow) * 1024;
  } else {
    K = 2048;
    Ab = (const ushort_t*)Ap + (size_t)(bm0 + srow) * 2048;
    Bf = (const float*)Bp + (size_t)(bn0 + srow) * 2048;
  }

  __shared__ ushort_t As[64 * 32];
  __shared__ ushort_t Bs[64 * 32];
  f32x4 acc00 = {0,0,0,0}, acc01 = {0,0,0,0}, acc10 = {0,0,0,0}, acc11 = {0,0,0,0};

  const int sstore = srow * 32 + ((sseg ^ (srow & 3)) << 3);
  const int ar0 = wr * 32 + fr,      ar1 = wr * 32 + 16 + fr;
  const int br0 = wc * 32 + fr,      br1 = wc * 32 + 16 + fr;
  const int aoff0 = ar0 * 32 + ((kseg ^ (ar0 & 3)) << 3);
  const int aoff1 = ar1 * 32 + ((kseg ^ (ar1 & 3)) << 3);
  const int boff0 = br0 * 32 + ((kseg ^ (br0 & 3)) << 3);
  const int boff1 = br1 * 32 + ((kseg ^ (br1 & 3)) << 3);

  for (int k0 = 0; k0 < K; k0 += 32) {
    s16x8 av, bv;
    if constexpr (MODE == 0) {
      const float* p = Af + k0 + sseg * 8;
      f32x4 x0 = *(const f32x4*)p, x1 = *(const f32x4*)(p + 4);
      av[0]=(short)f2bf(x0[0]); av[1]=(short)f2bf(x0[1]); av[2]=(short)f2bf(x0[2]); av[3]=(short)f2bf(x0[3]);
      av[4]=(short)f2bf(x1[0]); av[5]=(short)f2bf(x1[1]); av[6]=(short)f2bf(x1[2]); av[7]=(short)f2bf(x1[3]);
    } else {
      av = *(const s16x8*)(Ab + k0 + sseg * 8);
    }
    {
      const float* p = Bf + k0 + sseg * 8;
      f32x4 x0 = *(const f32x4*)p, x1 = *(const f32x4*)(p + 4);
      bv[0]=(short)f2bf(x0[0]); bv[1]=(short)f2bf(x0[1]); bv[2]=(short)f2bf(x0[2]); bv[3]=(short)f2bf(x0[3]);
      bv[4]=(short)f2bf(x1[0]); bv[5]=(short)f2bf(x1[1]); bv[6]=(short)f2bf(x1[2]); bv[7]=(short)f2bf(x1[3]);
    }
    *(s16x8*)&As[sstore] = av;
    *(s16x8*)&Bs[sstore] = bv;
    __syncthreads();
    s16x8 a0 = *(const s16x8*)&As[aoff0];
    s16x8 a1 = *(const s16x8*)&As[aoff1];
    s16x8 b0 = *(const s16x8*)&Bs[boff0];
    s16x8 b1 = *(const s16x8*)&Bs[boff1];
    acc00 = mfma16(a0, b0, acc00);
    acc01 = mfma16(a0, b1, acc01);
    acc10 = mfma16(a1, b0, acc10);
    acc11 = mfma16(a1, b1, acc11);
    __syncthreads();
  }

  const int mbase = bm0 + wr * 32 + kseg * 4;
  const int nbase = bn0 + wc * 32 + fr;
  auto wr4 = [&](f32x4 v, int m0, int n0) {
    #pragma unroll
    for (int r = 0; r < 4; ++r) {
      float x = v[r];
      if constexpr (MODE == 0)
        ((ushort_t*)Cp)[(size_t)(m0 + r) * 1024 + n0] = f2bf(x + bias1[n0] + bias2[n0]);
      else
        ((float*)Cp)[(size_t)(m0 + r) * 1024 + n0] = x;
    }
  };
  wr4(acc00, mbase,      nbase);
  wr4(acc01, mbase,      nbase + 16);
  wr4(acc10, mbase + 16, nbase);
  wr4(acc11, mbase + 16, nbase + 16);
}

// ---------------------------------------------------------------------------
// Persistent recurrence, weights REGISTER-RESIDENT, N-partitioned.
// 256 blocks x 512 thr (1 block/CU). Virtual N-space: 6144 cols of K=1024:
//   [0,1024)=z1p0 (wa1 k<1024), [1024,2048)=z1p1 (wa1 k>=1024),
//   [2048,6144)=gates (whh).
// Block bid: xcd=bid&7, r=bid>>3; r<24 -> owns cols vbase=xcd*768+r*32,
// holds its B[32n x 1024k] in 32 s16x8 frags/lane (128 VGPR) for the WHOLE
// kernel. Per step: 4 M-passes (64 batches: ds k-slice staged in LDS,
// swizzled) -> 8 waves x one 16x16 MFMA tile; device barrier; attn+softmax+
// y_tilde+LSTM for batch bid; device barrier.
// ---------------------------------------------------------------------------
__global__ __launch_bounds__(512, 2) void fused_loop3_k(
    ushort_t* __restrict__ dsbf, float* __restrict__ sst,
    const ushort_t* __restrict__ wa1, const ushort_t* __restrict__ whh,
    const ushort_t* __restrict__ z2bf,
    float* __restrict__ z1p0, float* __restrict__ z1p1, float* __restrict__ gates,
    const float* __restrict__ htw, const float* __restrict__ wa3,
    const float* __restrict__ y_seq, const float* __restrict__ Wt,
    const float* __restrict__ btld, const float* __restrict__ W_ih,
    const float* __restrict__ b_ih, const float* __restrict__ b_hh,
    float* __restrict__ betap, unsigned* __restrict__ bars)
{
  const int tid  = threadIdx.x;
  const int w    = tid >> 6;
  const int lane = tid & 63;
  const int fr   = lane & 15, kseg = lane >> 4;
  const int bid  = blockIdx.x;
  const int xcd  = bid & 7, r = bid >> 3;
  const int b    = bid;
  const bool gactive = (r < 24);

  __shared__ ushort_t As[64 * 1024];   // 128 KiB A-tile (64 batches x 1024 k), swizzled
  __shared__ float zs[64];
  __shared__ float yt_sh;

  // ---- GEMM geometry + persistent B fragments ----
  int koff = 0, cld = 1024, cn0 = 0; size_t ldb = 2048;
  const ushort_t* Bsrc = wa1; float* Cd = z1p0;
  if (gactive) {
    const int vbase = xcd * 768 + r * 32;
    if (vbase < 1024)      { Bsrc = wa1 + (size_t)vbase * 2048;               koff = 0;    ldb = 2048; Cd = z1p0;  cld = 1024; cn0 = vbase; }
    else if (vbase < 2048) { Bsrc = wa1 + (size_t)(vbase - 1024) * 2048 + 1024; koff = 1024; ldb = 2048; Cd = z1p1; cld = 1024; cn0 = vbase - 1024; }
    else                   { Bsrc = whh + (size_t)(vbase - 2048) * 1024;      koff = 0;    ldb = 1024; Cd = gates; cld = 4096; cn0 = vbase - 2048; }
  }
  const int msub = (w >> 1) * 16, nsub = (w & 1) * 16;

  s16x8 bfr[32];
  if (gactive) {
    const ushort_t* brow = Bsrc + (size_t)(nsub + fr) * ldb + kseg * 8;
    #pragma unroll
    for (int kk = 0; kk < 32; ++kk) bfr[kk] = *(const s16x8*)(brow + kk * 32);
  }
  const int arow = msub + fr;
  const int abase = arow * 1024, asw = arow & 7;

  for (int t = 0; t < 64; ++t) {
    // ================= GEMM phase =================
    if (gactive) {
      #pragma unroll 1
      for (int mt = 0; mt < 4; ++mt) {
        const int m0 = mt * 64;
        #pragma unroll
        for (int h2 = 0; h2 < 2; ++h2) {
          s16x8 tmp[8];
          #pragma unroll
          for (int it = 0; it < 8; ++it) {
            const int p = (h2 * 8 + it) * 512 + tid;
            const int row = p >> 7, c = p & 127;
            tmp[it] = *(const s16x8*)(dsbf + (size_t)(m0 + row) * 2048 + koff + c * 8);
          }
          #pragma unroll
          for (int it = 0; it < 8; ++it) {
            const int p = (h2 * 8 + it) * 512 + tid;
            const int row = p >> 7, c = p & 127;
            *(s16x8*)&As[row * 1024 + ((c ^ (row & 7)) << 3)] = tmp[it];
          }
        }
        __syncthreads();
        f32x4 acc = {0,0,0,0};
        #pragma unroll
        for (int kk = 0; kk < 32; ++kk) {
          const int cc = kk * 4 + kseg;
          s16x8 a = *(const s16x8*)&As[abase + ((cc ^ asw) << 3)];
          acc = mfma16(a, bfr[kk], acc);
        }
        const int orow = m0 + msub + kseg * 4;
        const int ocol = cn0 + nsub + fr;
        #pragma unroll
        for (int ri = 0; ri < 4; ++ri)
          Cd[(size_t)(orow + ri) * cld + ocol] = acc[ri];
        __syncthreads();
      }
    }
    dbar(bars + (size_t)(t * 2) * 256, xcd);

    // ================= attention phase (batch b = bid) =================
    float z1c[16], wc3[16];
    {
      const float* zp0 = z1p0 + (size_t)b * 1024 + lane * 16;
      const float* zp1 = z1p1 + (size_t)b * 1024 + lane * 16;
      const float* wp  = wa3 + lane * 16;
      #pragma unroll
      for (int q = 0; q < 16; q += 4) {
        f32x4 a0 = *(const f32x4*)(zp0 + q);
        f32x4 a1 = *(const f32x4*)(zp1 + q);
        f32x4 c  = *(const f32x4*)(wp + q);
        z1c[q]   = a0[0] + a1[0]; z1c[q+1] = a0[1] + a1[1];
        z1c[q+2] = a0[2] + a1[2]; z1c[q+3] = a0[3] + a1[3];
        wc3[q] = c[0]; wc3[q+1] = c[1]; wc3[q+2] = c[2]; wc3[q+3] = c[3];
      }
    }
    #pragma unroll
    for (int i = 0; i < 8; ++i) {
      const int tt = w * 8 + i;
      const ushort_t* zp = z2bf + (((size_t)(b * 64 + tt)) << 10) + lane * 16;
      s16x8 v0 = *(const s16x8*)zp;
      s16x8 v1 = *(const s16x8*)(zp + 8);
      float acc = 0.0f;
      #pragma unroll
      for (int q = 0; q < 8; ++q) acc = fmaf(fast_tanh(z1c[q]     + bf2f((ushort_t)v0[q])), wc3[q],     acc);
      #pragma unroll
      for (int q = 0; q < 8; ++q) acc = fmaf(fast_tanh(z1c[8 + q] + bf2f((ushort_t)v1[q])), wc3[8 + q], acc);
      #pragma unroll
      for (int m = 32; m >= 1; m >>= 1) acc += __shfl_xor(acc, m);
      if (lane == 0) zs[tt] = acc;
    }
    __syncthreads();

    if (w == 0) {
      float v = zs[lane];
      float mx = v;
      #pragma unroll
      for (int m = 32; m >= 1; m >>= 1) mx = fmaxf(mx, __shfl_xor(mx, m));
      float e = __expf(v - mx);
      float sum = e;
      #pragma unroll
      for (int m = 32; m >= 1; m >>= 1) sum += __shfl_xor(sum, m);
      float betav = e * frcp(sum);
      if (t == 63) betap[b * 64 + lane] = betav;
      float a = betav * htw[b * 64 + lane];
      #pragma unroll
      for (int m = 32; m >= 1; m >>= 1) a += __shfl_xor(a, m);
      if (lane == 0) yt_sh = fmaf(Wt[0], y_seq[b * 64 + t], a + btld[0]);
    }
    __syncthreads();

    if (t < 63) {
      const float ytv = yt_sh;
      const float* gb = gates + (size_t)b * 4096;
      #pragma unroll
      for (int rr = 0; rr < 2; ++rr) {
        const int hi = tid + rr * 512;
        float gi = gb[hi]        + ytv * W_ih[hi]        + b_ih[hi]        + b_hh[hi];
        float gf = gb[1024 + hi] + ytv * W_ih[1024 + hi] + b_ih[1024 + hi] + b_hh[1024 + hi];
        float gg = gb[2048 + hi] + ytv * W_ih[2048 + hi] + b_ih[2048 + hi] + b_hh[2048 + hi];
        float go = gb[3072 + hi] + ytv * W_ih[3072 + hi] + b_ih[3072 + hi] + b_hh[3072 + hi];
        float so = sst[(size_t)b * 1024 + hi];
        float ig = fast_sig(gi), fg = fast_sig(gf), gt = fast_tanh(gg), og = fast_sig(go);
        float sn = fmaf(fg, so, ig * gt);
        float dn = og * fast_tanh(sn);
        sst[(size_t)b * 1024 + hi] = sn;
        dsbf[(size_t)b * 2048 + hi] = f2bf(dn);
        dsbf[(size_t)b * 2048 + 1024 + hi] = f2bf(sn);
      }
      dbar(bars + (size_t)(t * 2 + 1) * 256, xcd);
    }
  }
}

// htw[b,t] = sum_c h[b,t,c] * W_tilde[1+c]
__global__ __launch_bounds__(256) void htw_k(const float* __restrict__ h, const float* __restrict__ Wt,
                                             float* __restrict__ htw)
{
  const int btx = blockIdx.x;
  const int tid = threadIdx.x;
  const float* hp = h + ((size_t)btx << 10);
  const int c = tid * 4;
  f32x4 hv = *(const f32x4*)(hp + c);
  float acc = hv[0]*Wt[1+c] + hv[1]*Wt[2+c] + hv[2]*Wt[3+c] + hv[3]*Wt[4+c];
  #pragma unroll
  for (int m = 32; m >= 1; m >>= 1) acc += __shfl_xor(acc, m);
  __shared__ float red[4];
  if ((tid & 63) == 0) red[tid >> 6] = acc;
  __syncthreads();
  if (tid == 0) htw[btx] = red[0] + red[1] + red[2] + red[3];
}

// ct[b,c] = sum_t beta[b,t]*h[b,t,c]; assemble dct = [d | ct] bf16
__global__ __launch_bounds__(256) void ct_k(const float* __restrict__ h, const float* __restrict__ beta,
                                            const ushort_t* __restrict__ ds_bf, ushort_t* __restrict__ dct)
{
  const int bid = blockIdx.x;
  const int b = bid >> 2, cb = bid & 3;
  const int c = cb * 256 + threadIdx.x;
  const float* hp = h + ((size_t)b << 16) + c;
  const float* bp = beta + b * 64;
  float acc = 0.0f;
  #pragma unroll 8
  for (int t = 0; t < 64; ++t) acc = fmaf(bp[t], hp[(size_t)t << 10], acc);
  dct[(size_t)b * 2048 + 1024 + c] = f2bf(acc);
  dct[(size_t)b * 2048 + c] = ds_bf[(size_t)b * 2048 + c];
}

// y[b] = sum_n (state[b,n]+b_fc1[n]) * W_fc2[n] + b_fc2   (f32 output)
__global__ __launch_bounds__(256) void head2_k(const float* __restrict__ state, const float* __restrict__ b_fc1,
                                               const float* __restrict__ W_fc2, const float* __restrict__ b_fc2,
                                               float* __restrict__ out)
{
  const int b = blockIdx.x, tid = threadIdx.x;
  const int c = tid * 4;
  f32x4 sv = *(const f32x4*)(state + ((size_t)b << 10) + c);
  f32x4 bv = *(const f32x4*)(b_fc1 + c);
  f32x4 wv = *(const f32x4*)(W_fc2 + c);
  float acc = (sv[0]+bv[0])*wv[0] + (sv[1]+bv[1])*wv[1] + (sv[2]+bv[2])*wv[2] + (sv[3]+bv[3])*wv[3];
  #pragma unroll
  for (int m = 32; m >= 1; m >>= 1) acc += __shfl_xor(acc, m);
  __shared__ float red[4];
  if ((tid & 63) == 0) red[tid >> 6] = acc;
  __syncthreads();
  if (tid == 0) out[b] = red[0] + red[1] + red[2] + red[3] + b_fc2[0];
}

__global__ void cvt_k(const float* __restrict__ in, ushort_t* __restrict__ out, int n)
{
  int i = (blockIdx.x * blockDim.x + threadIdx.x) * 4;
  const int stride = gridDim.x * blockDim.x * 4;
  for (; i < n; i += stride) {
    f32x4 v = *(const f32x4*)(in + i);
    u16x4 o; o[0] = f2bf(v[0]); o[1] = f2bf(v[1]); o[2] = f2bf(v[2]); o[3] = f2bf(v[3]);
    *(u16x4*)(out + i) = o;
  }
}

extern "C" void kernel_launch(void* const* d_in, const int* in_sizes, int n_in,
                              void* d_out, int out_size, void* d_ws, size_t ws_size,
                              hipStream_t stream)
{
  const float* h       = (const float*)d_in[0];
  const float* y_seq   = (const float*)d_in[1];
  const float* W_attn1 = (const float*)d_in[2];
  const float* b_attn1 = (const float*)d_in[3];
  const float* W_attn2 = (const float*)d_in[4];
  const float* b_attn2 = (const float*)d_in[5];
  const float* W_attn3 = (const float*)d_in[6];
  // d_in[7] = b_attn3: softmax shift-invariant, unused
  const float* W_ih    = (const float*)d_in[8];
  const float* W_hh    = (const float*)d_in[9];
  const float* b_ih    = (const float*)d_in[10];
  const float* b_hh    = (const float*)d_in[11];
  const float* W_tilde = (const float*)d_in[12];
  const float* b_tilde = (const float*)d_in[13];
  const float* W_fc1   = (const float*)d_in[14];
  const float* b_fc1   = (const float*)d_in[15];
  const float* W_fc2   = (const float*)d_in[16];
  const float* b_fc2   = (const float*)d_in[17];
  (void)in_sizes; (void)n_in; (void)out_size; (void)ws_size;

  char* ws = (char*)d_ws;
  ushort_t* z2bf   = (ushort_t*)(ws + 0);          // 33554432
  ushort_t* wa1bf  = (ushort_t*)(ws + 33554432);   //  4194304
  ushort_t* whhbf  = (ushort_t*)(ws + 37748736);   //  8388608
  float*    z1p0   = (float*)   (ws + 46137344);   //  1048576
  float*    z1p1   = (float*)   (ws + 47185920);   //  1048576
  float*    gatesp = (float*)   (ws + 48234496);   //  4194304
  ushort_t* dsbf   = (ushort_t*)(ws + 52428800);   //  1048576
  float*    sst    = (float*)   (ws + 53477376);   //  1048576
  float*    htwp   = (float*)   (ws + 54525952);   //    65536
  float*    betap  = (float*)   (ws + 54591488);   //    65536
  ushort_t* dctp   = (ushort_t*)(ws + 54657024);   //  1048576
  float*    statep = (float*)   (ws + 55705600);   //  1048576
  unsigned* bars   = (unsigned*)(ws + 56754176);   //   131072: 128 insts x 256 u32

  hipMemsetAsync(dsbf, 0, 1048576, stream);
  hipMemsetAsync(sst,  0, 1048576, stream);
  hipMemsetAsync(bars, 0, 131072, stream);
  cvt_k<<<dim3(256), dim3(256), 0, stream>>>(W_attn1, wa1bf, 2097152);
  cvt_k<<<dim3(256), dim3(256), 0, stream>>>(W_hh,    whhbf, 4194304);
  htw_k<<<dim3(16384), dim3(256), 0, stream>>>(h, W_tilde, htwp);
  gemm_bt_k<0><<<dim3(256, 16), dim3(256), 0, stream>>>(h, W_attn2, z2bf, b_attn1, b_attn2);

  void* kargs[] = {
    (void*)&dsbf, (void*)&sst, (void*)&wa1bf, (void*)&whhbf, (void*)&z2bf,
    (void*)&z1p0, (void*)&z1p1, (void*)&gatesp, (void*)&htwp, (void*)&W_attn3,
    (void*)&y_seq, (void*)&W_tilde, (void*)&b_tilde, (void*)&W_ih, (void*)&b_ih,
    (void*)&b_hh, (void*)&betap, (void*)&bars
  };
  hipLaunchCooperativeKernel((void*)fused_loop3_k, dim3(256), dim3(512), kargs, 0, stream);

  ct_k<<<dim3(1024), dim3(256), 0, stream>>>(h, betap, dsbf, dctp);
  gemm_bt_k<2><<<dim3(4, 16), dim3(256), 0, stream>>>(dctp, W_fc1, statep, nullptr, nullptr);
  head2_k<<<dim3(256), dim3(256), 0, stream>>>(statep, b_fc1, W_fc2, b_fc2, (float*)d_out);
}

// Round 6
// 9274.637 us; speedup vs baseline: 1.4307x; 1.4307x over previous
//
#include <hip/hip_runtime.h>

typedef unsigned short ushort_t;
typedef __attribute__((ext_vector_type(4))) float f32x4;
typedef __attribute__((ext_vector_type(8))) short s16x8;
typedef __attribute__((ext_vector_type(4))) unsigned short u16x4;
typedef __attribute__((ext_vector_type(8))) __bf16 bf16x8;

#define DEV __device__ __forceinline__

DEV float bf2f(ushort_t u){ union { unsigned int i; float f; } v; v.i = ((unsigned int)u) << 16; return v.f; }
DEV ushort_t f2bf(float f){
  union { float f; unsigned int i; } v; v.f = f;
  unsigned int r = v.i + 0x7FFFu + ((v.i >> 16) & 1u);   // RNE
  return (ushort_t)(r >> 16);
}
DEV float frcp(float x){
#if __has_builtin(__builtin_amdgcn_rcpf)
  return __builtin_amdgcn_rcpf(x);
#else
  return 1.0f / x;
#endif
}
DEV float fast_tanh(float x){
  x = fminf(9.0f, fmaxf(-9.0f, x));
  float e = __expf(2.0f * x);
  return fmaf(-2.0f, frcp(e + 1.0f), 1.0f);
}
DEV float fast_sig(float x){ return frcp(1.0f + __expf(-x)); }

DEV f32x4 mfma16(s16x8 a, s16x8 b, f32x4 c){
  return __builtin_amdgcn_mfma_f32_16x16x32_bf16(
      __builtin_bit_cast(bf16x8, a), __builtin_bit_cast(bf16x8, b), c, 0, 0, 0);
}

// Hierarchical device barrier over 256 blocks (fresh 2KB slot per use).
// Group g (=bid&7): 32 adds on group ctr; 32nd adds root; 8th root releases
// 8 flags (64B apart); everyone spins its group flag. Agent-scope acq_rel
// atomics carry happens-before for prior plain stores (verified r3-r5 pass).
DEV void dbar(unsigned* inst, int g){
  __syncthreads();
  if (threadIdx.x == 0) {
    unsigned old = __hip_atomic_fetch_add(inst + g * 16, 1u, __ATOMIC_ACQ_REL, __HIP_MEMORY_SCOPE_AGENT);
    if (old == 31u) {
      unsigned ro = __hip_atomic_fetch_add(inst + 256, 1u, __ATOMIC_ACQ_REL, __HIP_MEMORY_SCOPE_AGENT);
      if (ro == 7u) {
        #pragma unroll
        for (int i = 0; i < 8; ++i)
          __hip_atomic_store(inst + 288 + i * 16, 1u, __ATOMIC_RELEASE, __HIP_MEMORY_SCOPE_AGENT);
      }
    }
    while (__hip_atomic_load(inst + 288 + g * 16, __ATOMIC_ACQUIRE, __HIP_MEMORY_SCOPE_AGENT) == 0u)
      __builtin_amdgcn_s_sleep(2);
  }
  __syncthreads();
}

// ---------------------------------------------------------------------------
// One-shot GEMMs: C[m,n] = sum_k A[m,k]*B[n,k].
// MODE 0: A=h f32, B=W_attn2 f32 -> z2 bf16 (+b_attn1[n]+b_attn2[n])
// MODE 2: A=dct bf16 [256,2048], B=W_fc1 f32 [1024,2048] -> f32 [256,1024]
// ---------------------------------------------------------------------------
template<int MODE>
__global__ __launch_bounds__(256) void gemm_bt_k(
    const void* __restrict__ Ap, const void* __restrict__ Bp,
    void* __restrict__ Cp, const float* __restrict__ bias1, const float* __restrict__ bias2)
{
  const int bm0 = blockIdx.x * 64;
  const int bn0 = blockIdx.y * 64;
  const int tid = threadIdx.x;
  const int srow = tid >> 2, sseg = tid & 3;
  const int wid = tid >> 6, lane = tid & 63;
  const int wr = wid >> 1, wc = wid & 1;
  const int fr = lane & 15, kseg = lane >> 4;

  int K;
  const float* Af = nullptr; const ushort_t* Ab = nullptr;
  const float* Bf = nullptr;
  if constexpr (MODE == 0) {
    K = 1024;
    Af = (const float*)Ap + (size_t)(bm0 + srow) * 1024;
    Bf = (const float*)Bp + (size_t)(bn0 + srow) * 1024;
  } else {
    K = 2048;
    Ab = (const ushort_t*)Ap + (size_t)(bm0 + srow) * 2048;
    Bf = (const float*)Bp + (size_t)(bn0 + srow) * 2048;
  }

  __shared__ ushort_t As[64 * 32];
  __shared__ ushort_t Bs[64 * 32];
  f32x4 acc00 = {0,0,0,0}, acc01 = {0,0,0,0}, acc10 = {0,0,0,0}, acc11 = {0,0,0,0};

  const int sstore = srow * 32 + ((sseg ^ (srow & 3)) << 3);
  const int ar0 = wr * 32 + fr,      ar1 = wr * 32 + 16 + fr;
  const int br0 = wc * 32 + fr,      br1 = wc * 32 + 16 + fr;
  const int aoff0 = ar0 * 32 + ((kseg ^ (ar0 & 3)) << 3);
  const int aoff1 = ar1 * 32 + ((kseg ^ (ar1 & 3)) << 3);
  const int boff0 = br0 * 32 + ((kseg ^ (br0 & 3)) << 3);
  const int boff1 = br1 * 32 + ((kseg ^ (br1 & 3)) << 3);

  for (int k0 = 0; k0 < K; k0 += 32) {
    s16x8 av, bv;
    if constexpr (MODE == 0) {
      const float* p = Af + k0 + sseg * 8;
      f32x4 x0 = *(const f32x4*)p, x1 = *(const f32x4*)(p + 4);
      av[0]=(short)f2bf(x0[0]); av[1]=(short)f2bf(x0[1]); av[2]=(short)f2bf(x0[2]); av[3]=(short)f2bf(x0[3]);
      av[4]=(short)f2bf(x1[0]); av[5]=(short)f2bf(x1[1]); av[6]=(short)f2bf(x1[2]); av[7]=(short)f2bf(x1[3]);
    } else {
      av = *(const s16x8*)(Ab + k0 + sseg * 8);
    }
    {
      const float* p = Bf + k0 + sseg * 8;
      f32x4 x0 = *(const f32x4*)p, x1 = *(const f32x4*)(p + 4);
      bv[0]=(short)f2bf(x0[0]); bv[1]=(short)f2bf(x0[1]); bv[2]=(short)f2bf(x0[2]); bv[3]=(short)f2bf(x0[3]);
      bv[4]=(short)f2bf(x1[0]); bv[5]=(short)f2bf(x1[1]); bv[6]=(short)f2bf(x1[2]); bv[7]=(short)f2bf(x1[3]);
    }
    *(s16x8*)&As[sstore] = av;
    *(s16x8*)&Bs[sstore] = bv;
    __syncthreads();
    s16x8 a0 = *(const s16x8*)&As[aoff0];
    s16x8 a1 = *(const s16x8*)&As[aoff1];
    s16x8 b0 = *(const s16x8*)&Bs[boff0];
    s16x8 b1 = *(const s16x8*)&Bs[boff1];
    acc00 = mfma16(a0, b0, acc00);
    acc01 = mfma16(a0, b1, acc01);
    acc10 = mfma16(a1, b0, acc10);
    acc11 = mfma16(a1, b1, acc11);
    __syncthreads();
  }

  const int mbase = bm0 + wr * 32 + kseg * 4;
  const int nbase = bn0 + wc * 32 + fr;
  auto wr4 = [&](f32x4 v, int m0, int n0) {
    #pragma unroll
    for (int r = 0; r < 4; ++r) {
      float x = v[r];
      if constexpr (MODE == 0)
        ((ushort_t*)Cp)[(size_t)(m0 + r) * 1024 + n0] = f2bf(x + bias1[n0] + bias2[n0]);
      else
        ((float*)Cp)[(size_t)(m0 + r) * 1024 + n0] = x;
    }
  };
  wr4(acc00, mbase,      nbase);
  wr4(acc01, mbase,      nbase + 16);
  wr4(acc10, mbase + 16, nbase);
  wr4(acc11, mbase + 16, nbase + 16);
}

// ---------------------------------------------------------------------------
// Persistent recurrence, N-partitioned, weights LDS-RESIDENT (cannot spill).
// 256 blocks x 512 thr. Virtual N-space 6144 cols of K=1024:
//   [0,1024)=z1p0 (wa1 k<1024), [1024,2048)=z1p1 (wa1 k>=1024),
//   [2048,6144)=gates (whh).
// Block bid: xcd=bid&7, r=bid>>3; r<24 owns 32 cols (vbase=xcd*768+r*32),
// B panel [32n x 1024k] preloaded ONCE into 64KB LDS (XOR-swizzled).
// Per step: 8 waves x (32M x 32N x 1024K), A-frags read direct from global
// dsbf (1MB, L2-resident per XCD); dbar; per-batch attn+softmax+y_tilde+LSTM
// (batch = bid); dbar.
// ---------------------------------------------------------------------------
__global__ __launch_bounds__(512) void fused_loop4_k(
    ushort_t* __restrict__ dsbf, float* __restrict__ sst,
    const ushort_t* __restrict__ wa1, const ushort_t* __restrict__ whh,
    const ushort_t* __restrict__ z2bf,
    float* __restrict__ z1p0, float* __restrict__ z1p1, float* __restrict__ gates,
    const float* __restrict__ htw, const float* __restrict__ wa3,
    const float* __restrict__ y_seq, const float* __restrict__ Wt,
    const float* __restrict__ btld, const float* __restrict__ W_ih,
    const float* __restrict__ b_ih, const float* __restrict__ b_hh,
    float* __restrict__ betap, unsigned* __restrict__ bars)
{
  const int tid  = threadIdx.x;
  const int w    = tid >> 6;
  const int lane = tid & 63;
  const int fr   = lane & 15, kseg = lane >> 4;
  const int bid  = blockIdx.x;
  const int xcd  = bid & 7, r = bid >> 3;
  const int b    = bid;
  const bool ga  = (r < 24);

  __shared__ ushort_t Bs[32 * 1024];   // 64 KiB persistent B panel
  __shared__ float zs[64];
  __shared__ float yt_sh;

  // ---- geometry + one-time B-panel preload ----
  int koff = 0, cld = 1024, cn0 = 0; size_t ldb = 2048;
  const ushort_t* Bsrc = wa1; float* Cd = z1p0;
  if (ga) {
    const int vbase = xcd * 768 + r * 32;
    if (vbase < 1024)      { Bsrc = wa1 + (size_t)vbase * 2048;                 koff = 0;    ldb = 2048; Cd = z1p0;  cld = 1024; cn0 = vbase; }
    else if (vbase < 2048) { Bsrc = wa1 + (size_t)(vbase - 1024) * 2048 + 1024; koff = 1024; ldb = 2048; Cd = z1p1;  cld = 1024; cn0 = vbase - 1024; }
    else                   { Bsrc = whh + (size_t)(vbase - 2048) * 1024;        koff = 0;    ldb = 1024; Cd = gates; cld = 4096; cn0 = vbase - 2048; }
    #pragma unroll
    for (int it = 0; it < 8; ++it) {
      const int p = tid + it * 512;          // 4096 x 16B chunks
      const int row = p >> 7, c = p & 127;
      s16x8 v = *(const s16x8*)(Bsrc + (size_t)row * ldb + c * 8);
      *(s16x8*)&Bs[row * 1024 + ((c ^ (row & 7)) << 3)] = v;
    }
  }
  __syncthreads();

  // A-frag base pointers: wave w covers M-rows [w*32, w*32+32)
  const int m0 = w * 32;
  const ushort_t* a0p = dsbf + (size_t)(m0 + fr) * 2048 + koff + kseg * 8;
  const ushort_t* a1p = a0p + (size_t)16 * 2048;
  const int bsw0 = fr * 1024, bsw1 = (16 + fr) * 1024, bx = fr & 7;

  for (int t = 0; t < 64; ++t) {
    // ================= GEMM phase =================
    if (ga) {
      f32x4 acc00 = {0,0,0,0}, acc01 = {0,0,0,0}, acc10 = {0,0,0,0}, acc11 = {0,0,0,0};
      #pragma unroll
      for (int kk = 0; kk < 32; ++kk) {
        s16x8 a0 = *(const s16x8*)(a0p + kk * 32);
        s16x8 a1 = *(const s16x8*)(a1p + kk * 32);
        const int sw = ((kk * 4 + kseg) ^ bx) << 3;
        s16x8 b0 = *(const s16x8*)&Bs[bsw0 + sw];
        s16x8 b1 = *(const s16x8*)&Bs[bsw1 + sw];
        acc00 = mfma16(a0, b0, acc00);
        acc01 = mfma16(a0, b1, acc01);
        acc10 = mfma16(a1, b0, acc10);
        acc11 = mfma16(a1, b1, acc11);
      }
      const int orow = m0 + kseg * 4;
      const int ocol = cn0 + fr;
      #pragma unroll
      for (int ri = 0; ri < 4; ++ri) {
        Cd[(size_t)(orow + ri)      * cld + ocol]      = acc00[ri];
        Cd[(size_t)(orow + ri)      * cld + ocol + 16] = acc01[ri];
        Cd[(size_t)(orow + ri + 16) * cld + ocol]      = acc10[ri];
        Cd[(size_t)(orow + ri + 16) * cld + ocol + 16] = acc11[ri];
      }
    }
    dbar(bars + (size_t)(t * 2) * 512, xcd);

    // ================= attention phase (batch b = bid) =================
    float z1c[16], wc3[16];
    {
      const float* zp0 = z1p0 + (size_t)b * 1024 + lane * 16;
      const float* zp1 = z1p1 + (size_t)b * 1024 + lane * 16;
      const float* wp  = wa3 + lane * 16;
      #pragma unroll
      for (int q = 0; q < 16; q += 4) {
        f32x4 a0 = *(const f32x4*)(zp0 + q);
        f32x4 a1 = *(const f32x4*)(zp1 + q);
        f32x4 c  = *(const f32x4*)(wp + q);
        z1c[q]   = a0[0] + a1[0]; z1c[q+1] = a0[1] + a1[1];
        z1c[q+2] = a0[2] + a1[2]; z1c[q+3] = a0[3] + a1[3];
        wc3[q] = c[0]; wc3[q+1] = c[1]; wc3[q+2] = c[2]; wc3[q+3] = c[3];
      }
    }
    #pragma unroll
    for (int i = 0; i < 8; ++i) {
      const int tt = w * 8 + i;
      const ushort_t* zp = z2bf + (((size_t)(b * 64 + tt)) << 10) + lane * 16;
      s16x8 v0 = *(const s16x8*)zp;
      s16x8 v1 = *(const s16x8*)(zp + 8);
      float acc = 0.0f;
      #pragma unroll
      for (int q = 0; q < 8; ++q) acc = fmaf(fast_tanh(z1c[q]     + bf2f((ushort_t)v0[q])), wc3[q],     acc);
      #pragma unroll
      for (int q = 0; q < 8; ++q) acc = fmaf(fast_tanh(z1c[8 + q] + bf2f((ushort_t)v1[q])), wc3[8 + q], acc);
      #pragma unroll
      for (int m = 32; m >= 1; m >>= 1) acc += __shfl_xor(acc, m);
      if (lane == 0) zs[tt] = acc;
    }
    __syncthreads();

    if (w == 0) {
      float v = zs[lane];
      float mx = v;
      #pragma unroll
      for (int m = 32; m >= 1; m >>= 1) mx = fmaxf(mx, __shfl_xor(mx, m));
      float e = __expf(v - mx);
      float sum = e;
      #pragma unroll
      for (int m = 32; m >= 1; m >>= 1) sum += __shfl_xor(sum, m);
      float betav = e * frcp(sum);
      if (t == 63) betap[b * 64 + lane] = betav;
      float a = betav * htw[b * 64 + lane];
      #pragma unroll
      for (int m = 32; m >= 1; m >>= 1) a += __shfl_xor(a, m);
      if (lane == 0) yt_sh = fmaf(Wt[0], y_seq[b * 64 + t], a + btld[0]);
    }
    __syncthreads();

    if (t < 63) {
      const float ytv = yt_sh;
      const float* gb = gates + (size_t)b * 4096;
      #pragma unroll
      for (int rr = 0; rr < 2; ++rr) {
        const int hi = tid + rr * 512;
        float gi = gb[hi]        + ytv * W_ih[hi]        + b_ih[hi]        + b_hh[hi];
        float gf = gb[1024 + hi] + ytv * W_ih[1024 + hi] + b_ih[1024 + hi] + b_hh[1024 + hi];
        float gg = gb[2048 + hi] + ytv * W_ih[2048 + hi] + b_ih[2048 + hi] + b_hh[2048 + hi];
        float go = gb[3072 + hi] + ytv * W_ih[3072 + hi] + b_ih[3072 + hi] + b_hh[3072 + hi];
        float so = sst[(size_t)b * 1024 + hi];
        float ig = fast_sig(gi), fg = fast_sig(gf), gt = fast_tanh(gg), og = fast_sig(go);
        float sn = fmaf(fg, so, ig * gt);
        float dn = og * fast_tanh(sn);
        sst[(size_t)b * 1024 + hi] = sn;
        dsbf[(size_t)b * 2048 + hi] = f2bf(dn);
        dsbf[(size_t)b * 2048 + 1024 + hi] = f2bf(sn);
      }
      dbar(bars + (size_t)(t * 2 + 1) * 512, xcd);
    }
  }
}

// htw[b,t] = sum_c h[b,t,c] * W_tilde[1+c]
__global__ __launch_bounds__(256) void htw_k(const float* __restrict__ h, const float* __restrict__ Wt,
                                             float* __restrict__ htw)
{
  const int btx = blockIdx.x;
  const int tid = threadIdx.x;
  const float* hp = h + ((size_t)btx << 10);
  const int c = tid * 4;
  f32x4 hv = *(const f32x4*)(hp + c);
  float acc = hv[0]*Wt[1+c] + hv[1]*Wt[2+c] + hv[2]*Wt[3+c] + hv[3]*Wt[4+c];
  #pragma unroll
  for (int m = 32; m >= 1; m >>= 1) acc += __shfl_xor(acc, m);
  __shared__ float red[4];
  if ((tid & 63) == 0) red[tid >> 6] = acc;
  __syncthreads();
  if (tid == 0) htw[btx] = red[0] + red[1] + red[2] + red[3];
}

// ct[b,c] = sum_t beta[b,t]*h[b,t,c]; assemble dct = [d | ct] bf16
__global__ __launch_bounds__(256) void ct_k(const float* __restrict__ h, const float* __restrict__ beta,
                                            const ushort_t* __restrict__ ds_bf, ushort_t* __restrict__ dct)
{
  const int bid = blockIdx.x;
  const int b = bid >> 2, cb = bid & 3;
  const int c = cb * 256 + threadIdx.x;
  const float* hp = h + ((size_t)b << 16) + c;
  const float* bp = beta + b * 64;
  float acc = 0.0f;
  #pragma unroll 8
  for (int t = 0; t < 64; ++t) acc = fmaf(bp[t], hp[(size_t)t << 10], acc);
  dct[(size_t)b * 2048 + 1024 + c] = f2bf(acc);
  dct[(size_t)b * 2048 + c] = ds_bf[(size_t)b * 2048 + c];
}

// y[b] = sum_n (state[b,n]+b_fc1[n]) * W_fc2[n] + b_fc2   (f32 output)
__global__ __launch_bounds__(256) void head2_k(const float* __restrict__ state, const float* __restrict__ b_fc1,
                                               const float* __restrict__ W_fc2, const float* __restrict__ b_fc2,
                                               float* __restrict__ out)
{
  const int b = blockIdx.x, tid = threadIdx.x;
  const int c = tid * 4;
  f32x4 sv = *(const f32x4*)(state + ((size_t)b << 10) + c);
  f32x4 bv = *(const f32x4*)(b_fc1 + c);
  f32x4 wv = *(const f32x4*)(W_fc2 + c);
  float acc = (sv[0]+bv[0])*wv[0] + (sv[1]+bv[1])*wv[1] + (sv[2]+bv[2])*wv[2] + (sv[3]+bv[3])*wv[3];
  #pragma unroll
  for (int m = 32; m >= 1; m >>= 1) acc += __shfl_xor(acc, m);
  __shared__ float red[4];
  if ((tid & 63) == 0) red[tid >> 6] = acc;
  __syncthreads();
  if (tid == 0) out[b] = red[0] + red[1] + red[2] + red[3] + b_fc2[0];
}

__global__ void cvt_k(const float* __restrict__ in, ushort_t* __restrict__ out, int n)
{
  int i = (blockIdx.x * blockDim.x + threadIdx.x) * 4;
  const int stride = gridDim.x * blockDim.x * 4;
  for (; i < n; i += stride) {
    f32x4 v = *(const f32x4*)(in + i);
    u16x4 o; o[0] = f2bf(v[0]); o[1] = f2bf(v[1]); o[2] = f2bf(v[2]); o[3] = f2bf(v[3]);
    *(u16x4*)(out + i) = o;
  }
}

extern "C" void kernel_launch(void* const* d_in, const int* in_sizes, int n_in,
                              void* d_out, int out_size, void* d_ws, size_t ws_size,
                              hipStream_t stream)
{
  const float* h       = (const float*)d_in[0];
  const float* y_seq   = (const float*)d_in[1];
  const float* W_attn1 = (const float*)d_in[2];
  const float* b_attn1 = (const float*)d_in[3];
  const float* W_attn2 = (const float*)d_in[4];
  const float* b_attn2 = (const float*)d_in[5];
  const float* W_attn3 = (const float*)d_in[6];
  // d_in[7] = b_attn3: softmax shift-invariant, unused
  const float* W_ih    = (const float*)d_in[8];
  const float* W_hh    = (const float*)d_in[9];
  const float* b_ih    = (const float*)d_in[10];
  const float* b_hh    = (const float*)d_in[11];
  const float* W_tilde = (const float*)d_in[12];
  const float* b_tilde = (const float*)d_in[13];
  const float* W_fc1   = (const float*)d_in[14];
  const float* b_fc1   = (const float*)d_in[15];
  const float* W_fc2   = (const float*)d_in[16];
  const float* b_fc2   = (const float*)d_in[17];
  (void)in_sizes; (void)n_in; (void)out_size; (void)ws_size;

  char* ws = (char*)d_ws;
  ushort_t* z2bf   = (ushort_t*)(ws + 0);          // 33554432
  ushort_t* wa1bf  = (ushort_t*)(ws + 33554432);   //  4194304
  ushort_t* whhbf  = (ushort_t*)(ws + 37748736);   //  8388608
  float*    z1p0   = (float*)   (ws + 46137344);   //  1048576
  float*    z1p1   = (float*)   (ws + 47185920);   //  1048576
  float*    gatesp = (float*)   (ws + 48234496);   //  4194304
  ushort_t* dsbf   = (ushort_t*)(ws + 52428800);   //  1048576
  float*    sst    = (float*)   (ws + 53477376);   //  1048576
  float*    htwp   = (float*)   (ws + 54525952);   //    65536
  float*    betap  = (float*)   (ws + 54591488);   //    65536
  ushort_t* dctp   = (ushort_t*)(ws + 54657024);   //  1048576
  float*    statep = (float*)   (ws + 55705600);   //  1048576
  unsigned* bars   = (unsigned*)(ws + 56754176);   //   262144: 128 insts x 512 u32

  hipMemsetAsync(dsbf, 0, 1048576, stream);
  hipMemsetAsync(sst,  0, 1048576, stream);
  hipMemsetAsync(bars, 0, 262144, stream);
  cvt_k<<<dim3(256), dim3(256), 0, stream>>>(W_attn1, wa1bf, 2097152);
  cvt_k<<<dim3(256), dim3(256), 0, stream>>>(W_hh,    whhbf, 4194304);
  htw_k<<<dim3(16384), dim3(256), 0, stream>>>(h, W_tilde, htwp);
  gemm_bt_k<0><<<dim3(256, 16), dim3(256), 0, stream>>>(h, W_attn2, z2bf, b_attn1, b_attn2);

  void* kargs[] = {
    (void*)&dsbf, (void*)&sst, (void*)&wa1bf, (void*)&whhbf, (void*)&z2bf,
    (void*)&z1p0, (void*)&z1p1, (void*)&gatesp, (void*)&htwp, (void*)&W_attn3,
    (void*)&y_seq, (void*)&W_tilde, (void*)&b_tilde, (void*)&W_ih, (void*)&b_ih,
    (void*)&b_hh, (void*)&betap, (void*)&bars
  };
  hipLaunchCooperativeKernel((void*)fused_loop4_k, dim3(256), dim3(512), kargs, 0, stream);

  ct_k<<<dim3(1024), dim3(256), 0, stream>>>(h, betap, dsbf, dctp);
  gemm_bt_k<2><<<dim3(4, 16), dim3(256), 0, stream>>>(dctp, W_fc1, statep, nullptr, nullptr);
  head2_k<<<dim3(256), dim3(256), 0, stream>>>(statep, b_fc1, W_fc2, b_fc2, (float*)d_out);
}

// Round 7
// 4300.515 us; speedup vs baseline: 3.0855x; 2.1566x over previous
//
#include <hip/hip_runtime.h>

typedef unsigned short ushort_t;
typedef __attribute__((ext_vector_type(4))) float f32x4;
typedef __attribute__((ext_vector_type(8))) short s16x8;
typedef __attribute__((ext_vector_type(4))) unsigned short u16x4;
typedef __attribute__((ext_vector_type(8))) __bf16 bf16x8;

#define DEV __device__ __forceinline__

DEV float bf2f(ushort_t u){ union { unsigned int i; float f; } v; v.i = ((unsigned int)u) << 16; return v.f; }
DEV ushort_t f2bf(float f){
  union { float f; unsigned int i; } v; v.f = f;
  unsigned int r = v.i + 0x7FFFu + ((v.i >> 16) & 1u);   // RNE
  return (ushort_t)(r >> 16);
}
DEV float frcp(float x){
#if __has_builtin(__builtin_amdgcn_rcpf)
  return __builtin_amdgcn_rcpf(x);
#else
  return 1.0f / x;
#endif
}
DEV float fast_tanh(float x){
  x = fminf(9.0f, fmaxf(-9.0f, x));
  float e = __expf(2.0f * x);
  return fmaf(-2.0f, frcp(e + 1.0f), 1.0f);
}
DEV float fast_sig(float x){ return frcp(1.0f + __expf(-x)); }

DEV f32x4 mfma16(s16x8 a, s16x8 b, f32x4 c){
  return __builtin_amdgcn_mfma_f32_16x16x32_bf16(
      __builtin_bit_cast(bf16x8, a), __builtin_bit_cast(bf16x8, b), c, 0, 0, 0);
}

// Hierarchical device barrier over 256 blocks (fresh 2KB slot per use).
// Arrival: RELEASE fetch_add (writes back producer L2 once). Spin: RELAXED
// loads (no per-iteration L2 invalidate). Exit: ONE ACQUIRE load -> single
// L2 inv per barrier. RMW release-sequences carry happens-before.
DEV void dbar(unsigned* inst, int g){
  __syncthreads();
  if (threadIdx.x == 0) {
    unsigned old = __hip_atomic_fetch_add(inst + g * 16, 1u, __ATOMIC_RELEASE, __HIP_MEMORY_SCOPE_AGENT);
    if (old == 31u) {
      unsigned ro = __hip_atomic_fetch_add(inst + 256, 1u, __ATOMIC_ACQ_REL, __HIP_MEMORY_SCOPE_AGENT);
      if (ro == 7u) {
        #pragma unroll
        for (int i = 0; i < 8; ++i)
          __hip_atomic_store(inst + 288 + i * 16, 1u, __ATOMIC_RELEASE, __HIP_MEMORY_SCOPE_AGENT);
      }
    }
    while (__hip_atomic_load(inst + 288 + g * 16, __ATOMIC_RELAXED, __HIP_MEMORY_SCOPE_AGENT) == 0u)
      __builtin_amdgcn_s_sleep(8);
    (void)__hip_atomic_load(inst + 288 + g * 16, __ATOMIC_ACQUIRE, __HIP_MEMORY_SCOPE_AGENT);
  }
  __syncthreads();
}

// ---------------------------------------------------------------------------
// One-shot GEMMs: C[m,n] = sum_k A[m,k]*B[n,k].
// MODE 0: A=h f32, B=W_attn2 f32 -> z2 bf16 (+b_attn1[n]+b_attn2[n])
// MODE 2: A=dct bf16 [256,2048], B=W_fc1 f32 [1024,2048] -> f32 [256,1024]
// ---------------------------------------------------------------------------
template<int MODE>
__global__ __launch_bounds__(256) void gemm_bt_k(
    const void* __restrict__ Ap, const void* __restrict__ Bp,
    void* __restrict__ Cp, const float* __restrict__ bias1, const float* __restrict__ bias2)
{
  const int bm0 = blockIdx.x * 64;
  const int bn0 = blockIdx.y * 64;
  const int tid = threadIdx.x;
  const int srow = tid >> 2, sseg = tid & 3;
  const int wid = tid >> 6, lane = tid & 63;
  const int wr = wid >> 1, wc = wid & 1;
  const int fr = lane & 15, kseg = lane >> 4;

  int K;
  const float* Af = nullptr; const ushort_t* Ab = nullptr;
  const float* Bf = nullptr;
  if constexpr (MODE == 0) {
    K = 1024;
    Af = (const float*)Ap + (size_t)(bm0 + srow) * 1024;
    Bf = (const float*)Bp + (size_t)(bn0 + srow) * 1024;
  } else {
    K = 2048;
    Ab = (const ushort_t*)Ap + (size_t)(bm0 + srow) * 2048;
    Bf = (const float*)Bp + (size_t)(bn0 + srow) * 2048;
  }

  __shared__ ushort_t As[64 * 32];
  __shared__ ushort_t Bs[64 * 32];
  f32x4 acc00 = {0,0,0,0}, acc01 = {0,0,0,0}, acc10 = {0,0,0,0}, acc11 = {0,0,0,0};

  const int sstore = srow * 32 + ((sseg ^ (srow & 3)) << 3);
  const int ar0 = wr * 32 + fr,      ar1 = wr * 32 + 16 + fr;
  const int br0 = wc * 32 + fr,      br1 = wc * 32 + 16 + fr;
  const int aoff0 = ar0 * 32 + ((kseg ^ (ar0 & 3)) << 3);
  const int aoff1 = ar1 * 32 + ((kseg ^ (ar1 & 3)) << 3);
  const int boff0 = br0 * 32 + ((kseg ^ (br0 & 3)) << 3);
  const int boff1 = br1 * 32 + ((kseg ^ (br1 & 3)) << 3);

  for (int k0 = 0; k0 < K; k0 += 32) {
    s16x8 av, bv;
    if constexpr (MODE == 0) {
      const float* p = Af + k0 + sseg * 8;
      f32x4 x0 = *(const f32x4*)p, x1 = *(const f32x4*)(p + 4);
      av[0]=(short)f2bf(x0[0]); av[1]=(short)f2bf(x0[1]); av[2]=(short)f2bf(x0[2]); av[3]=(short)f2bf(x0[3]);
      av[4]=(short)f2bf(x1[0]); av[5]=(short)f2bf(x1[1]); av[6]=(short)f2bf(x1[2]); av[7]=(short)f2bf(x1[3]);
    } else {
      av = *(const s16x8*)(Ab + k0 + sseg * 8);
    }
    {
      const float* p = Bf + k0 + sseg * 8;
      f32x4 x0 = *(const f32x4*)p, x1 = *(const f32x4*)(p + 4);
      bv[0]=(short)f2bf(x0[0]); bv[1]=(short)f2bf(x0[1]); bv[2]=(short)f2bf(x0[2]); bv[3]=(short)f2bf(x0[3]);
      bv[4]=(short)f2bf(x1[0]); bv[5]=(short)f2bf(x1[1]); bv[6]=(short)f2bf(x1[2]); bv[7]=(short)f2bf(x1[3]);
    }
    *(s16x8*)&As[sstore] = av;
    *(s16x8*)&Bs[sstore] = bv;
    __syncthreads();
    s16x8 a0 = *(const s16x8*)&As[aoff0];
    s16x8 a1 = *(const s16x8*)&As[aoff1];
    s16x8 b0 = *(const s16x8*)&Bs[boff0];
    s16x8 b1 = *(const s16x8*)&Bs[boff1];
    acc00 = mfma16(a0, b0, acc00);
    acc01 = mfma16(a0, b1, acc01);
    acc10 = mfma16(a1, b0, acc10);
    acc11 = mfma16(a1, b1, acc11);
    __syncthreads();
  }

  const int mbase = bm0 + wr * 32 + kseg * 4;
  const int nbase = bn0 + wc * 32 + fr;
  auto wr4 = [&](f32x4 v, int m0, int n0) {
    #pragma unroll
    for (int r = 0; r < 4; ++r) {
      float x = v[r];
      if constexpr (MODE == 0)
        ((ushort_t*)Cp)[(size_t)(m0 + r) * 1024 + n0] = f2bf(x + bias1[n0] + bias2[n0]);
      else
        ((float*)Cp)[(size_t)(m0 + r) * 1024 + n0] = x;
    }
  };
  wr4(acc00, mbase,      nbase);
  wr4(acc01, mbase,      nbase + 16);
  wr4(acc10, mbase + 16, nbase);
  wr4(acc11, mbase + 16, nbase + 16);
}

// ---------------------------------------------------------------------------
// Persistent recurrence. N-partitioned GEMM with LDS-resident weights
// (round-6 structure) + z2 VGPR-RESIDENT (16 s16x8/lane) so the barrier's
// L2 invalidation never forces a z2 re-fetch. s-state lives in 2 VGPRs.
// ---------------------------------------------------------------------------
__global__ __launch_bounds__(512) __attribute__((amdgpu_waves_per_eu(2, 2)))
void fused_loop5_k(
    ushort_t* __restrict__ dsbf,
    const ushort_t* __restrict__ wa1, const ushort_t* __restrict__ whh,
    const ushort_t* __restrict__ z2bf,
    float* __restrict__ z1p0, float* __restrict__ z1p1, float* __restrict__ gates,
    const float* __restrict__ htw, const float* __restrict__ wa3,
    const float* __restrict__ y_seq, const float* __restrict__ Wt,
    const float* __restrict__ btld, const float* __restrict__ W_ih,
    const float* __restrict__ b_ih, const float* __restrict__ b_hh,
    float* __restrict__ betap, unsigned* __restrict__ bars)
{
  const int tid  = threadIdx.x;
  const int w    = tid >> 6;
  const int lane = tid & 63;
  const int fr   = lane & 15, kseg = lane >> 4;
  const int bid  = blockIdx.x;
  const int xcd  = bid & 7, r = bid >> 3;
  const int b    = bid;
  const bool ga  = (r < 24);

  __shared__ ushort_t Bs[32 * 1024];   // 64 KiB persistent B panel
  __shared__ float zs[64];
  __shared__ float ys_sh[64];
  __shared__ float yt_sh;

  // ---- geometry + one-time B-panel preload ----
  int koff = 0, cld = 1024, cn0 = 0; size_t ldb = 2048;
  const ushort_t* Bsrc = wa1; float* Cd = z1p0;
  if (ga) {
    const int vbase = xcd * 768 + r * 32;
    if (vbase < 1024)      { Bsrc = wa1 + (size_t)vbase * 2048;                 koff = 0;    ldb = 2048; Cd = z1p0;  cld = 1024; cn0 = vbase; }
    else if (vbase < 2048) { Bsrc = wa1 + (size_t)(vbase - 1024) * 2048 + 1024; koff = 1024; ldb = 2048; Cd = z1p1;  cld = 1024; cn0 = vbase - 1024; }
    else                   { Bsrc = whh + (size_t)(vbase - 2048) * 1024;        koff = 0;    ldb = 1024; Cd = gates; cld = 4096; cn0 = vbase - 2048; }
    #pragma unroll
    for (int it = 0; it < 8; ++it) {
      const int p = tid + it * 512;          // 4096 x 16B chunks
      const int row = p >> 7, c = p & 127;
      s16x8 v = *(const s16x8*)(Bsrc + (size_t)row * ldb + c * 8);
      *(s16x8*)&Bs[row * 1024 + ((c ^ (row & 7)) << 3)] = v;
    }
  }
  if (tid < 64) ys_sh[tid] = y_seq[b * 64 + tid];

  // ---- one-time per-lane resident state ----
  // z2 slice: wave w, rows tt=w*8..w*8+7, cols lane*16..+15  (64 VGPR)
  s16x8 z2r[16];
  {
    const ushort_t* zb = z2bf + (((size_t)(b * 64 + w * 8)) << 10) + lane * 16;
    #pragma unroll
    for (int i = 0; i < 8; ++i) {
      z2r[2 * i]     = *(const s16x8*)(zb + ((size_t)i << 10));
      z2r[2 * i + 1] = *(const s16x8*)(zb + ((size_t)i << 10) + 8);
    }
  }
  float wc3[16];
  {
    const float* wp = wa3 + lane * 16;
    #pragma unroll
    for (int q = 0; q < 16; q += 4) {
      f32x4 c = *(const f32x4*)(wp + q);
      wc3[q] = c[0]; wc3[q+1] = c[1]; wc3[q+2] = c[2]; wc3[q+3] = c[3];
    }
  }
  float wih0[4], bsum0[4], wih1[4], bsum1[4];
  #pragma unroll
  for (int q = 0; q < 4; ++q) {
    wih0[q] = W_ih[q * 1024 + tid];       bsum0[q] = b_ih[q * 1024 + tid] + b_hh[q * 1024 + tid];
    wih1[q] = W_ih[q * 1024 + tid + 512]; bsum1[q] = b_ih[q * 1024 + tid + 512] + b_hh[q * 1024 + tid + 512];
  }
  const float htwv = htw[b * 64 + lane];
  const float Wt0 = Wt[0], bt0 = btld[0];
  float s0v = 0.0f, s1v = 0.0f;          // s-state f32, block-local
  __syncthreads();

  // A-frag base pointers: wave w covers M-rows [w*32, w*32+32)
  const int m0 = w * 32;
  const ushort_t* a0p = dsbf + (size_t)(m0 + fr) * 2048 + koff + kseg * 8;
  const ushort_t* a1p = a0p + (size_t)16 * 2048;
  const int bsw0 = fr * 1024, bsw1 = (16 + fr) * 1024, bx = fr & 7;

  for (int t = 0; t < 64; ++t) {
    // ================= GEMM phase =================
    if (ga) {
      f32x4 acc00 = {0,0,0,0}, acc01 = {0,0,0,0}, acc10 = {0,0,0,0}, acc11 = {0,0,0,0};
      #pragma unroll
      for (int kk = 0; kk < 32; ++kk) {
        s16x8 a0 = *(const s16x8*)(a0p + kk * 32);
        s16x8 a1 = *(const s16x8*)(a1p + kk * 32);
        const int sw = ((kk * 4 + kseg) ^ bx) << 3;
        s16x8 b0 = *(const s16x8*)&Bs[bsw0 + sw];
        s16x8 b1 = *(const s16x8*)&Bs[bsw1 + sw];
        acc00 = mfma16(a0, b0, acc00);
        acc01 = mfma16(a0, b1, acc01);
        acc10 = mfma16(a1, b0, acc10);
        acc11 = mfma16(a1, b1, acc11);
      }
      const int orow = m0 + kseg * 4;
      const int ocol = cn0 + fr;
      #pragma unroll
      for (int ri = 0; ri < 4; ++ri) {
        Cd[(size_t)(orow + ri)      * cld + ocol]      = acc00[ri];
        Cd[(size_t)(orow + ri)      * cld + ocol + 16] = acc01[ri];
        Cd[(size_t)(orow + ri + 16) * cld + ocol]      = acc10[ri];
        Cd[(size_t)(orow + ri + 16) * cld + ocol + 16] = acc11[ri];
      }
    }
    dbar(bars + (size_t)(t * 2) * 512, xcd);

    // ================= attention phase (batch b = bid) =================
    float z1c[16];
    {
      const float* zp0 = z1p0 + (size_t)b * 1024 + lane * 16;
      const float* zp1 = z1p1 + (size_t)b * 1024 + lane * 16;
      #pragma unroll
      for (int q = 0; q < 16; q += 4) {
        f32x4 a0 = *(const f32x4*)(zp0 + q);
        f32x4 a1 = *(const f32x4*)(zp1 + q);
        z1c[q]   = a0[0] + a1[0]; z1c[q+1] = a0[1] + a1[1];
        z1c[q+2] = a0[2] + a1[2]; z1c[q+3] = a0[3] + a1[3];
      }
    }
    #pragma unroll
    for (int i = 0; i < 8; ++i) {
      const int tt = w * 8 + i;
      s16x8 v0 = z2r[2 * i];
      s16x8 v1 = z2r[2 * i + 1];
      float acc = 0.0f;
      #pragma unroll
      for (int q = 0; q < 8; ++q) acc = fmaf(fast_tanh(z1c[q]     + bf2f((ushort_t)v0[q])), wc3[q],     acc);
      #pragma unroll
      for (int q = 0; q < 8; ++q) acc = fmaf(fast_tanh(z1c[8 + q] + bf2f((ushort_t)v1[q])), wc3[8 + q], acc);
      #pragma unroll
      for (int m = 32; m >= 1; m >>= 1) acc += __shfl_xor(acc, m);
      if (lane == 0) zs[tt] = acc;
    }
    __syncthreads();

    if (w == 0) {
      float v = zs[lane];
      float mx = v;
      #pragma unroll
      for (int m = 32; m >= 1; m >>= 1) mx = fmaxf(mx, __shfl_xor(mx, m));
      float e = __expf(v - mx);
      float sum = e;
      #pragma unroll
      for (int m = 32; m >= 1; m >>= 1) sum += __shfl_xor(sum, m);
      float betav = e * frcp(sum);
      if (t == 63) betap[b * 64 + lane] = betav;
      float a = betav * htwv;
      #pragma unroll
      for (int m = 32; m >= 1; m >>= 1) a += __shfl_xor(a, m);
      if (lane == 0) yt_sh = fmaf(Wt0, ys_sh[t], a + bt0);
    }
    __syncthreads();

    if (t < 63) {
      const float ytv = yt_sh;
      const float* gb = gates + (size_t)b * 4096;
      {
        float gi = gb[tid]        + ytv * wih0[0] + bsum0[0];
        float gf = gb[1024 + tid] + ytv * wih0[1] + bsum0[1];
        float gg = gb[2048 + tid] + ytv * wih0[2] + bsum0[2];
        float go = gb[3072 + tid] + ytv * wih0[3] + bsum0[3];
        float ig = fast_sig(gi), fg = fast_sig(gf), gt = fast_tanh(gg), og = fast_sig(go);
        float sn = fmaf(fg, s0v, ig * gt);
        float dn = og * fast_tanh(sn);
        s0v = sn;
        dsbf[(size_t)b * 2048 + tid] = f2bf(dn);
        dsbf[(size_t)b * 2048 + 1024 + tid] = f2bf(sn);
      }
      {
        const int hi = tid + 512;
        float gi = gb[hi]        + ytv * wih1[0] + bsum1[0];
        float gf = gb[1024 + hi] + ytv * wih1[1] + bsum1[1];
        float gg = gb[2048 + hi] + ytv * wih1[2] + bsum1[2];
        float go = gb[3072 + hi] + ytv * wih1[3] + bsum1[3];
        float ig = fast_sig(gi), fg = fast_sig(gf), gt = fast_tanh(gg), og = fast_sig(go);
        float sn = fmaf(fg, s1v, ig * gt);
        float dn = og * fast_tanh(sn);
        s1v = sn;
        dsbf[(size_t)b * 2048 + hi] = f2bf(dn);
        dsbf[(size_t)b * 2048 + 1024 + hi] = f2bf(sn);
      }
      dbar(bars + (size_t)(t * 2 + 1) * 512, xcd);
    }
  }
}

// htw[b,t] = sum_c h[b,t,c] * W_tilde[1+c]
__global__ __launch_bounds__(256) void htw_k(const float* __restrict__ h, const float* __restrict__ Wt,
                                             float* __restrict__ htw)
{
  const int btx = blockIdx.x;
  const int tid = threadIdx.x;
  const float* hp = h + ((size_t)btx << 10);
  const int c = tid * 4;
  f32x4 hv = *(const f32x4*)(hp + c);
  float acc = hv[0]*Wt[1+c] + hv[1]*Wt[2+c] + hv[2]*Wt[3+c] + hv[3]*Wt[4+c];
  #pragma unroll
  for (int m = 32; m >= 1; m >>= 1) acc += __shfl_xor(acc, m);
  __shared__ float red[4];
  if ((tid & 63) == 0) red[tid >> 6] = acc;
  __syncthreads();
  if (tid == 0) htw[btx] = red[0] + red[1] + red[2] + red[3];
}

// ct[b,c] = sum_t beta[b,t]*h[b,t,c]; assemble dct = [d | ct] bf16
__global__ __launch_bounds__(256) void ct_k(const float* __restrict__ h, const float* __restrict__ beta,
                                            const ushort_t* __restrict__ ds_bf, ushort_t* __restrict__ dct)
{
  const int bid = blockIdx.x;
  const int b = bid >> 2, cb = bid & 3;
  const int c = cb * 256 + threadIdx.x;
  const float* hp = h + ((size_t)b << 16) + c;
  const float* bp = beta + b * 64;
  float acc = 0.0f;
  #pragma unroll 8
  for (int t = 0; t < 64; ++t) acc = fmaf(bp[t], hp[(size_t)t << 10], acc);
  dct[(size_t)b * 2048 + 1024 + c] = f2bf(acc);
  dct[(size_t)b * 2048 + c] = ds_bf[(size_t)b * 2048 + c];
}

// y[b] = sum_n (state[b,n]+b_fc1[n]) * W_fc2[n] + b_fc2   (f32 output)
__global__ __launch_bounds__(256) void head2_k(const float* __restrict__ state, const float* __restrict__ b_fc1,
                                               const float* __restrict__ W_fc2, const float* __restrict__ b_fc2,
                                               float* __restrict__ out)
{
  const int b = blockIdx.x, tid = threadIdx.x;
  const int c = tid * 4;
  f32x4 sv = *(const f32x4*)(state + ((size_t)b << 10) + c);
  f32x4 bv = *(const f32x4*)(b_fc1 + c);
  f32x4 wv = *(const f32x4*)(W_fc2 + c);
  float acc = (sv[0]+bv[0])*wv[0] + (sv[1]+bv[1])*wv[1] + (sv[2]+bv[2])*wv[2] + (sv[3]+bv[3])*wv[3];
  #pragma unroll
  for (int m = 32; m >= 1; m >>= 1) acc += __shfl_xor(acc, m);
  __shared__ float red[4];
  if ((tid & 63) == 0) red[tid >> 6] = acc;
  __syncthreads();
  if (tid == 0) out[b] = red[0] + red[1] + red[2] + red[3] + b_fc2[0];
}

__global__ void cvt_k(const float* __restrict__ in, ushort_t* __restrict__ out, int n)
{
  int i = (blockIdx.x * blockDim.x + threadIdx.x) * 4;
  const int stride = gridDim.x * blockDim.x * 4;
  for (; i < n; i += stride) {
    f32x4 v = *(const f32x4*)(in + i);
    u16x4 o; o[0] = f2bf(v[0]); o[1] = f2bf(v[1]); o[2] = f2bf(v[2]); o[3] = f2bf(v[3]);
    *(u16x4*)(out + i) = o;
  }
}

extern "C" void kernel_launch(void* const* d_in, const int* in_sizes, int n_in,
                              void* d_out, int out_size, void* d_ws, size_t ws_size,
                              hipStream_t stream)
{
  const float* h       = (const float*)d_in[0];
  const float* y_seq   = (const float*)d_in[1];
  const float* W_attn1 = (const float*)d_in[2];
  const float* b_attn1 = (const float*)d_in[3];
  const float* W_attn2 = (const float*)d_in[4];
  const float* b_attn2 = (const float*)d_in[5];
  const float* W_attn3 = (const float*)d_in[6];
  // d_in[7] = b_attn3: softmax shift-invariant, unused
  const float* W_ih    = (const float*)d_in[8];
  const float* W_hh    = (const float*)d_in[9];
  const float* b_ih    = (const float*)d_in[10];
  const float* b_hh    = (const float*)d_in[11];
  const float* W_tilde = (const float*)d_in[12];
  const float* b_tilde = (const float*)d_in[13];
  const float* W_fc1   = (const float*)d_in[14];
  const float* b_fc1   = (const float*)d_in[15];
  const float* W_fc2   = (const float*)d_in[16];
  const float* b_fc2   = (const float*)d_in[17];
  (void)in_sizes; (void)n_in; (void)out_size; (void)ws_size;

  char* ws = (char*)d_ws;
  ushort_t* z2bf   = (ushort_t*)(ws + 0);          // 33554432
  ushort_t* wa1bf  = (ushort_t*)(ws + 33554432);   //  4194304
  ushort_t* whhbf  = (ushort_t*)(ws + 37748736);   //  8388608
  float*    z1p0   = (float*)   (ws + 46137344);   //  1048576
  float*    z1p1   = (float*)   (ws + 47185920);   //  1048576
  float*    gatesp = (float*)   (ws + 48234496);   //  4194304
  ushort_t* dsbf   = (ushort_t*)(ws + 52428800);   //  1048576
  float*    htwp   = (float*)   (ws + 54525952);   //    65536
  float*    betap  = (float*)   (ws + 54591488);   //    65536
  ushort_t* dctp   = (ushort_t*)(ws + 54657024);   //  1048576
  float*    statep = (float*)   (ws + 55705600);   //  1048576
  unsigned* bars   = (unsigned*)(ws + 56754176);   //   262144: 128 insts x 512 u32

  hipMemsetAsync(dsbf, 0, 1048576, stream);
  hipMemsetAsync(bars, 0, 262144, stream);
  cvt_k<<<dim3(256), dim3(256), 0, stream>>>(W_attn1, wa1bf, 2097152);
  cvt_k<<<dim3(256), dim3(256), 0, stream>>>(W_hh,    whhbf, 4194304);
  htw_k<<<dim3(16384), dim3(256), 0, stream>>>(h, W_tilde, htwp);
  gemm_bt_k<0><<<dim3(256, 16), dim3(256), 0, stream>>>(h, W_attn2, z2bf, b_attn1, b_attn2);

  void* kargs[] = {
    (void*)&dsbf, (void*)&wa1bf, (void*)&whhbf, (void*)&z2bf,
    (void*)&z1p0, (void*)&z1p1, (void*)&gatesp, (void*)&htwp, (void*)&W_attn3,
    (void*)&y_seq, (void*)&W_tilde, (void*)&b_tilde, (void*)&W_ih, (void*)&b_ih,
    (void*)&b_hh, (void*)&betap, (void*)&bars
  };
  hipLaunchCooperativeKernel((void*)fused_loop5_k, dim3(256), dim3(512), kargs, 0, stream);

  ct_k<<<dim3(1024), dim3(256), 0, stream>>>(h, betap, dsbf, dctp);
  gemm_bt_k<2><<<dim3(4, 16), dim3(256), 0, stream>>>(dctp, W_fc1, statep, nullptr, nullptr);
  head2_k<<<dim3(256), dim3(256), 0, stream>>>(statep, b_fc1, W_fc2, b_fc2, (float*)d_out);
}

// Round 8
// 4056.136 us; speedup vs baseline: 3.2714x; 1.0602x over previous
//
#include <hip/hip_runtime.h>

typedef unsigned short ushort_t;
typedef __attribute__((ext_vector_type(4))) float f32x4;
typedef __attribute__((ext_vector_type(8))) short s16x8;
typedef __attribute__((ext_vector_type(4))) unsigned short u16x4;
typedef __attribute__((ext_vector_type(8))) __bf16 bf16x8;

#define DEV __device__ __forceinline__

DEV float bf2f(ushort_t u){ union { unsigned int i; float f; } v; v.i = ((unsigned int)u) << 16; return v.f; }
DEV ushort_t f2bf(float f){
  union { float f; unsigned int i; } v; v.f = f;
  unsigned int r = v.i + 0x7FFFu + ((v.i >> 16) & 1u);   // RNE
  return (ushort_t)(r >> 16);
}
DEV float frcp(float x){
#if __has_builtin(__builtin_amdgcn_rcpf)
  return __builtin_amdgcn_rcpf(x);
#else
  return 1.0f / x;
#endif
}
DEV float fast_tanh(float x){
  x = fminf(9.0f, fmaxf(-9.0f, x));
  float e = __expf(2.0f * x);
  return fmaf(-2.0f, frcp(e + 1.0f), 1.0f);
}
DEV float fast_sig(float x){ return frcp(1.0f + __expf(-x)); }

DEV f32x4 mfma16(s16x8 a, s16x8 b, f32x4 c){
  return __builtin_amdgcn_mfma_f32_16x16x32_bf16(
      __builtin_bit_cast(bf16x8, a), __builtin_bit_cast(bf16x8, b), c, 0, 0, 0);
}

// Hierarchical device barrier over 256 blocks (fresh 2KB slot per use).
// Arrival: RELEASE fetch_add. Spin: RELAXED loads (no per-iter L2 inv).
// Exit: ONE ACQUIRE load -> single L2 inv per barrier. (verified r4-r7)
DEV void dbar(unsigned* inst, int g){
  __syncthreads();
  if (threadIdx.x == 0) {
    unsigned old = __hip_atomic_fetch_add(inst + g * 16, 1u, __ATOMIC_RELEASE, __HIP_MEMORY_SCOPE_AGENT);
    if (old == 31u) {
      unsigned ro = __hip_atomic_fetch_add(inst + 256, 1u, __ATOMIC_ACQ_REL, __HIP_MEMORY_SCOPE_AGENT);
      if (ro == 7u) {
        #pragma unroll
        for (int i = 0; i < 8; ++i)
          __hip_atomic_store(inst + 288 + i * 16, 1u, __ATOMIC_RELEASE, __HIP_MEMORY_SCOPE_AGENT);
      }
    }
    while (__hip_atomic_load(inst + 288 + g * 16, __ATOMIC_RELAXED, __HIP_MEMORY_SCOPE_AGENT) == 0u)
      __builtin_amdgcn_s_sleep(8);
    (void)__hip_atomic_load(inst + 288 + g * 16, __ATOMIC_ACQUIRE, __HIP_MEMORY_SCOPE_AGENT);
  }
  __syncthreads();
}

// ---------------------------------------------------------------------------
// One-shot GEMMs: C[m,n] = sum_k A[m,k]*B[n,k].
// MODE 0: A=h f32, B=W_attn2 f32 -> z2 bf16 (+b_attn1[n]+b_attn2[n])
// MODE 2: A=dct bf16 [256,2048], B=W_fc1 f32 [1024,2048] -> f32 [256,1024]
// ---------------------------------------------------------------------------
template<int MODE>
__global__ __launch_bounds__(256) void gemm_bt_k(
    const void* __restrict__ Ap, const void* __restrict__ Bp,
    void* __restrict__ Cp, const float* __restrict__ bias1, const float* __restrict__ bias2)
{
  const int bm0 = blockIdx.x * 64;
  const int bn0 = blockIdx.y * 64;
  const int tid = threadIdx.x;
  const int srow = tid >> 2, sseg = tid & 3;
  const int wid = tid >> 6, lane = tid & 63;
  const int wr = wid >> 1, wc = wid & 1;
  const int fr = lane & 15, kseg = lane >> 4;

  int K;
  const float* Af = nullptr; const ushort_t* Ab = nullptr;
  const float* Bf = nullptr;
  if constexpr (MODE == 0) {
    K = 1024;
    Af = (const float*)Ap + (size_t)(bm0 + srow) * 1024;
    Bf = (const float*)Bp + (size_t)(bn0 + srow) * 1024;
  } else {
    K = 2048;
    Ab = (const ushort_t*)Ap + (size_t)(bm0 + srow) * 2048;
    Bf = (const float*)Bp + (size_t)(bn0 + srow) * 2048;
  }

  __shared__ ushort_t As[64 * 32];
  __shared__ ushort_t Bs[64 * 32];
  f32x4 acc00 = {0,0,0,0}, acc01 = {0,0,0,0}, acc10 = {0,0,0,0}, acc11 = {0,0,0,0};

  const int sstore = srow * 32 + ((sseg ^ (srow & 3)) << 3);
  const int ar0 = wr * 32 + fr,      ar1 = wr * 32 + 16 + fr;
  const int br0 = wc * 32 + fr,      br1 = wc * 32 + 16 + fr;
  const int aoff0 = ar0 * 32 + ((kseg ^ (ar0 & 3)) << 3);
  const int aoff1 = ar1 * 32 + ((kseg ^ (ar1 & 3)) << 3);
  const int boff0 = br0 * 32 + ((kseg ^ (br0 & 3)) << 3);
  const int boff1 = br1 * 32 + ((kseg ^ (br1 & 3)) << 3);

  for (int k0 = 0; k0 < K; k0 += 32) {
    s16x8 av, bv;
    if constexpr (MODE == 0) {
      const float* p = Af + k0 + sseg * 8;
      f32x4 x0 = *(const f32x4*)p, x1 = *(const f32x4*)(p + 4);
      av[0]=(short)f2bf(x0[0]); av[1]=(short)f2bf(x0[1]); av[2]=(short)f2bf(x0[2]); av[3]=(short)f2bf(x0[3]);
      av[4]=(short)f2bf(x1[0]); av[5]=(short)f2bf(x1[1]); av[6]=(short)f2bf(x1[2]); av[7]=(short)f2bf(x1[3]);
    } else {
      av = *(const s16x8*)(Ab + k0 + sseg * 8);
    }
    {
      const float* p = Bf + k0 + sseg * 8;
      f32x4 x0 = *(const f32x4*)p, x1 = *(const f32x4*)(p + 4);
      bv[0]=(short)f2bf(x0[0]); bv[1]=(short)f2bf(x0[1]); bv[2]=(short)f2bf(x0[2]); bv[3]=(short)f2bf(x0[3]);
      bv[4]=(short)f2bf(x1[0]); bv[5]=(short)f2bf(x1[1]); bv[6]=(short)f2bf(x1[2]); bv[7]=(short)f2bf(x1[3]);
    }
    *(s16x8*)&As[sstore] = av;
    *(s16x8*)&Bs[sstore] = bv;
    __syncthreads();
    s16x8 a0 = *(const s16x8*)&As[aoff0];
    s16x8 a1 = *(const s16x8*)&As[aoff1];
    s16x8 b0 = *(const s16x8*)&Bs[boff0];
    s16x8 b1 = *(const s16x8*)&Bs[boff1];
    acc00 = mfma16(a0, b0, acc00);
    acc01 = mfma16(a0, b1, acc01);
    acc10 = mfma16(a1, b0, acc10);
    acc11 = mfma16(a1, b1, acc11);
    __syncthreads();
  }

  const int mbase = bm0 + wr * 32 + kseg * 4;
  const int nbase = bn0 + wc * 32 + fr;
  auto wr4 = [&](f32x4 v, int m0, int n0) {
    #pragma unroll
    for (int r = 0; r < 4; ++r) {
      float x = v[r];
      if constexpr (MODE == 0)
        ((ushort_t*)Cp)[(size_t)(m0 + r) * 1024 + n0] = f2bf(x + bias1[n0] + bias2[n0]);
      else
        ((float*)Cp)[(size_t)(m0 + r) * 1024 + n0] = x;
    }
  };
  wr4(acc00, mbase,      nbase);
  wr4(acc01, mbase,      nbase + 16);
  wr4(acc10, mbase + 16, nbase);
  wr4(acc11, mbase + 16, nbase + 16);
}

// ---------------------------------------------------------------------------
// Persistent recurrence. N-partitioned GEMM, LDS-resident weights, z2
// VGPR-resident. __launch_bounds__(512,2) -> 256-VGPR budget (fix round-7
// spill). wa3 / W_ih / (b_ih+b_hh) moved to LDS to shed ~35 VGPRs of
// pressure; gates prefetched right after the first barrier.
// ---------------------------------------------------------------------------
__global__ __launch_bounds__(512, 2)
void fused_loop6_k(
    ushort_t* __restrict__ dsbf,
    const ushort_t* __restrict__ wa1, const ushort_t* __restrict__ whh,
    const ushort_t* __restrict__ z2bf,
    float* __restrict__ z1p0, float* __restrict__ z1p1, float* __restrict__ gates,
    const float* __restrict__ htw, const float* __restrict__ wa3,
    const float* __restrict__ y_seq, const float* __restrict__ Wt,
    const float* __restrict__ btld, const float* __restrict__ W_ih,
    const float* __restrict__ b_ih, const float* __restrict__ b_hh,
    float* __restrict__ betap, unsigned* __restrict__ bars)
{
  const int tid  = threadIdx.x;
  const int w    = tid >> 6;
  const int lane = tid & 63;
  const int fr   = lane & 15, kseg = lane >> 4;
  const int bid  = blockIdx.x;
  const int xcd  = bid & 7, r = bid >> 3;
  const int b    = bid;
  const bool ga  = (r < 24);

  __shared__ ushort_t Bs[32 * 1024];   // 64 KiB persistent B panel
  __shared__ float wa3s[1024];         //  4 KiB
  __shared__ float wihs[4096];         // 16 KiB
  __shared__ float bsums[4096];        // 16 KiB  (b_ih + b_hh)
  __shared__ float zs[64];
  __shared__ float ys_sh[64];
  __shared__ float yt_sh;

  // ---- geometry + one-time B-panel preload ----
  int koff = 0, cld = 1024, cn0 = 0; size_t ldb = 2048;
  const ushort_t* Bsrc = wa1; float* Cd = z1p0;
  if (ga) {
    const int vbase = xcd * 768 + r * 32;
    if (vbase < 1024)      { Bsrc = wa1 + (size_t)vbase * 2048;                 koff = 0;    ldb = 2048; Cd = z1p0;  cld = 1024; cn0 = vbase; }
    else if (vbase < 2048) { Bsrc = wa1 + (size_t)(vbase - 1024) * 2048 + 1024; koff = 1024; ldb = 2048; Cd = z1p1;  cld = 1024; cn0 = vbase - 1024; }
    else                   { Bsrc = whh + (size_t)(vbase - 2048) * 1024;        koff = 0;    ldb = 1024; Cd = gates; cld = 4096; cn0 = vbase - 2048; }
    #pragma unroll
    for (int it = 0; it < 8; ++it) {
      const int p = tid + it * 512;          // 4096 x 16B chunks
      const int row = p >> 7, c = p & 127;
      s16x8 v = *(const s16x8*)(Bsrc + (size_t)row * ldb + c * 8);
      *(s16x8*)&Bs[row * 1024 + ((c ^ (row & 7)) << 3)] = v;
    }
  }
  // ---- shared small constants ----
  #pragma unroll
  for (int i = tid; i < 1024; i += 512) wa3s[i] = wa3[i];
  #pragma unroll
  for (int i = tid; i < 4096; i += 512) { wihs[i] = W_ih[i]; bsums[i] = b_ih[i] + b_hh[i]; }
  if (tid < 64) ys_sh[tid] = y_seq[b * 64 + tid];

  // ---- per-lane resident state ----
  // z2 slice: wave w, rows tt=w*8..w*8+7, cols lane*16..+15  (64 VGPR)
  s16x8 z2r[16];
  {
    const ushort_t* zb = z2bf + (((size_t)(b * 64 + w * 8)) << 10) + lane * 16;
    #pragma unroll
    for (int i = 0; i < 8; ++i) {
      z2r[2 * i]     = *(const s16x8*)(zb + ((size_t)i << 10));
      z2r[2 * i + 1] = *(const s16x8*)(zb + ((size_t)i << 10) + 8);
    }
  }
  const float htwv = htw[b * 64 + lane];
  const float Wt0 = Wt[0], bt0 = btld[0];
  float s0v = 0.0f, s1v = 0.0f;          // s-state f32, block-local
  __syncthreads();

  // A-frag base pointers: wave w covers M-rows [w*32, w*32+32)
  const int m0 = w * 32;
  const ushort_t* a0p = dsbf + (size_t)(m0 + fr) * 2048 + koff + kseg * 8;
  const ushort_t* a1p = a0p + (size_t)16 * 2048;
  const int bsw0 = fr * 1024, bsw1 = (16 + fr) * 1024, bx = fr & 7;

  for (int t = 0; t < 64; ++t) {
    // ================= GEMM phase =================
    if (ga) {
      f32x4 acc00 = {0,0,0,0}, acc01 = {0,0,0,0}, acc10 = {0,0,0,0}, acc11 = {0,0,0,0};
      #pragma unroll
      for (int kk = 0; kk < 32; ++kk) {
        s16x8 a0 = *(const s16x8*)(a0p + kk * 32);
        s16x8 a1 = *(const s16x8*)(a1p + kk * 32);
        const int sw = ((kk * 4 + kseg) ^ bx) << 3;
        s16x8 b0 = *(const s16x8*)&Bs[bsw0 + sw];
        s16x8 b1 = *(const s16x8*)&Bs[bsw1 + sw];
        acc00 = mfma16(a0, b0, acc00);
        acc01 = mfma16(a0, b1, acc01);
        acc10 = mfma16(a1, b0, acc10);
        acc11 = mfma16(a1, b1, acc11);
      }
      const int orow = m0 + kseg * 4;
      const int ocol = cn0 + fr;
      #pragma unroll
      for (int ri = 0; ri < 4; ++ri) {
        Cd[(size_t)(orow + ri)      * cld + ocol]      = acc00[ri];
        Cd[(size_t)(orow + ri)      * cld + ocol + 16] = acc01[ri];
        Cd[(size_t)(orow + ri + 16) * cld + ocol]      = acc10[ri];
        Cd[(size_t)(orow + ri + 16) * cld + ocol + 16] = acc11[ri];
      }
    }
    dbar(bars + (size_t)(t * 2) * 512, xcd);

    // ---- prefetch this step's gate pre-activations (hide post-inv latency)
    float gp0 = 0, gp1 = 0, gp2 = 0, gp3 = 0, gp4 = 0, gp5 = 0, gp6 = 0, gp7 = 0;
    if (t < 63) {
      const float* gb = gates + (size_t)b * 4096;
      gp0 = gb[tid];        gp1 = gb[1024 + tid];
      gp2 = gb[2048 + tid]; gp3 = gb[3072 + tid];
      gp4 = gb[512 + tid];  gp5 = gb[1536 + tid];
      gp6 = gb[2560 + tid]; gp7 = gb[3584 + tid];
    }

    // ================= attention phase (batch b = bid) =================
    float z1c[16], wc3[16];
    {
      const float* zp0 = z1p0 + (size_t)b * 1024 + lane * 16;
      const float* zp1 = z1p1 + (size_t)b * 1024 + lane * 16;
      #pragma unroll
      for (int q = 0; q < 16; q += 4) {
        f32x4 a0 = *(const f32x4*)(zp0 + q);
        f32x4 a1 = *(const f32x4*)(zp1 + q);
        f32x4 c  = *(const f32x4*)(&wa3s[lane * 16 + q]);
        z1c[q]   = a0[0] + a1[0]; z1c[q+1] = a0[1] + a1[1];
        z1c[q+2] = a0[2] + a1[2]; z1c[q+3] = a0[3] + a1[3];
        wc3[q] = c[0]; wc3[q+1] = c[1]; wc3[q+2] = c[2]; wc3[q+3] = c[3];
      }
    }
    #pragma unroll
    for (int i = 0; i < 8; ++i) {
      s16x8 v0 = z2r[2 * i];
      s16x8 v1 = z2r[2 * i + 1];
      float acc = 0.0f;
      #pragma unroll
      for (int q = 0; q < 8; ++q) acc = fmaf(fast_tanh(z1c[q]     + bf2f((ushort_t)v0[q])), wc3[q],     acc);
      #pragma unroll
      for (int q = 0; q < 8; ++q) acc = fmaf(fast_tanh(z1c[8 + q] + bf2f((ushort_t)v1[q])), wc3[8 + q], acc);
      #pragma unroll
      for (int m = 32; m >= 1; m >>= 1) acc += __shfl_xor(acc, m);
      if (lane == 0) zs[w * 8 + i] = acc;
    }
    __syncthreads();

    if (w == 0) {
      float v = zs[lane];
      float mx = v;
      #pragma unroll
      for (int m = 32; m >= 1; m >>= 1) mx = fmaxf(mx, __shfl_xor(mx, m));
      float e = __expf(v - mx);
      float sum = e;
      #pragma unroll
      for (int m = 32; m >= 1; m >>= 1) sum += __shfl_xor(sum, m);
      float betav = e * frcp(sum);
      if (t == 63) betap[b * 64 + lane] = betav;
      float a = betav * htwv;
      #pragma unroll
      for (int m = 32; m >= 1; m >>= 1) a += __shfl_xor(a, m);
      if (lane == 0) yt_sh = fmaf(Wt0, ys_sh[t], a + bt0);
    }
    __syncthreads();

    if (t < 63) {
      const float ytv = yt_sh;
      {
        float gi = gp0 + ytv * wihs[tid]        + bsums[tid];
        float gf = gp1 + ytv * wihs[1024 + tid] + bsums[1024 + tid];
        float gg = gp2 + ytv * wihs[2048 + tid] + bsums[2048 + tid];
        float go = gp3 + ytv * wihs[3072 + tid] + bsums[3072 + tid];
        float ig = fast_sig(gi), fg = fast_sig(gf), gt = fast_tanh(gg), og = fast_sig(go);
        float sn = fmaf(fg, s0v, ig * gt);
        float dn = og * fast_tanh(sn);
        s0v = sn;
        dsbf[(size_t)b * 2048 + tid] = f2bf(dn);
        dsbf[(size_t)b * 2048 + 1024 + tid] = f2bf(sn);
      }
      {
        const int hi = tid + 512;
        float gi = gp4 + ytv * wihs[hi]        + bsums[hi];
        float gf = gp5 + ytv * wihs[1024 + hi] + bsums[1024 + hi];
        float gg = gp6 + ytv * wihs[2048 + hi] + bsums[2048 + hi];
        float go = gp7 + ytv * wihs[3072 + hi] + bsums[3072 + hi];
        float ig = fast_sig(gi), fg = fast_sig(gf), gt = fast_tanh(gg), og = fast_sig(go);
        float sn = fmaf(fg, s1v, ig * gt);
        float dn = og * fast_tanh(sn);
        s1v = sn;
        dsbf[(size_t)b * 2048 + hi] = f2bf(dn);
        dsbf[(size_t)b * 2048 + 1024 + hi] = f2bf(sn);
      }
      dbar(bars + (size_t)(t * 2 + 1) * 512, xcd);
    }
  }
}

// htw[b,t] = sum_c h[b,t,c] * W_tilde[1+c]
__global__ __launch_bounds__(256) void htw_k(const float* __restrict__ h, const float* __restrict__ Wt,
                                             float* __restrict__ htw)
{
  const int btx = blockIdx.x;
  const int tid = threadIdx.x;
  const float* hp = h + ((size_t)btx << 10);
  const int c = tid * 4;
  f32x4 hv = *(const f32x4*)(hp + c);
  float acc = hv[0]*Wt[1+c] + hv[1]*Wt[2+c] + hv[2]*Wt[3+c] + hv[3]*Wt[4+c];
  #pragma unroll
  for (int m = 32; m >= 1; m >>= 1) acc += __shfl_xor(acc, m);
  __shared__ float red[4];
  if ((tid & 63) == 0) red[tid >> 6] = acc;
  __syncthreads();
  if (tid == 0) htw[btx] = red[0] + red[1] + red[2] + red[3];
}

// ct[b,c] = sum_t beta[b,t]*h[b,t,c]; assemble dct = [d | ct] bf16
__global__ __launch_bounds__(256) void ct_k(const float* __restrict__ h, const float* __restrict__ beta,
                                            const ushort_t* __restrict__ ds_bf, ushort_t* __restrict__ dct)
{
  const int bid = blockIdx.x;
  const int b = bid >> 2, cb = bid & 3;
  const int c = cb * 256 + threadIdx.x;
  const float* hp = h + ((size_t)b << 16) + c;
  const float* bp = beta + b * 64;
  float acc = 0.0f;
  #pragma unroll 8
  for (int t = 0; t < 64; ++t) acc = fmaf(bp[t], hp[(size_t)t << 10], acc);
  dct[(size_t)b * 2048 + 1024 + c] = f2bf(acc);
  dct[(size_t)b * 2048 + c] = ds_bf[(size_t)b * 2048 + c];
}

// y[b] = sum_n (state[b,n]+b_fc1[n]) * W_fc2[n] + b_fc2   (f32 output)
__global__ __launch_bounds__(256) void head2_k(const float* __restrict__ state, const float* __restrict__ b_fc1,
                                               const float* __restrict__ W_fc2, const float* __restrict__ b_fc2,
                                               float* __restrict__ out)
{
  const int b = blockIdx.x, tid = threadIdx.x;
  const int c = tid * 4;
  f32x4 sv = *(const f32x4*)(state + ((size_t)b << 10) + c);
  f32x4 bv = *(const f32x4*)(b_fc1 + c);
  f32x4 wv = *(const f32x4*)(W_fc2 + c);
  float acc = (sv[0]+bv[0])*wv[0] + (sv[1]+bv[1])*wv[1] + (sv[2]+bv[2])*wv[2] + (sv[3]+bv[3])*wv[3];
  #pragma unroll
  for (int m = 32; m >= 1; m >>= 1) acc += __shfl_xor(acc, m);
  __shared__ float red[4];
  if ((tid & 63) == 0) red[tid >> 6] = acc;
  __syncthreads();
  if (tid == 0) out[b] = red[0] + red[1] + red[2] + red[3] + b_fc2[0];
}

__global__ void cvt_k(const float* __restrict__ in, ushort_t* __restrict__ out, int n)
{
  int i = (blockIdx.x * blockDim.x + threadIdx.x) * 4;
  const int stride = gridDim.x * blockDim.x * 4;
  for (; i < n; i += stride) {
    f32x4 v = *(const f32x4*)(in + i);
    u16x4 o; o[0] = f2bf(v[0]); o[1] = f2bf(v[1]); o[2] = f2bf(v[2]); o[3] = f2bf(v[3]);
    *(u16x4*)(out + i) = o;
  }
}

extern "C" void kernel_launch(void* const* d_in, const int* in_sizes, int n_in,
                              void* d_out, int out_size, void* d_ws, size_t ws_size,
                              hipStream_t stream)
{
  const float* h       = (const float*)d_in[0];
  const float* y_seq   = (const float*)d_in[1];
  const float* W_attn1 = (const float*)d_in[2];
  const float* b_attn1 = (const float*)d_in[3];
  const float* W_attn2 = (const float*)d_in[4];
  const float* b_attn2 = (const float*)d_in[5];
  const float* W_attn3 = (const float*)d_in[6];
  // d_in[7] = b_attn3: softmax shift-invariant, unused
  const float* W_ih    = (const float*)d_in[8];
  const float* W_hh    = (const float*)d_in[9];
  const float* b_ih    = (const float*)d_in[10];
  const float* b_hh    = (const float*)d_in[11];
  const float* W_tilde = (const float*)d_in[12];
  const float* b_tilde = (const float*)d_in[13];
  const float* W_fc1   = (const float*)d_in[14];
  const float* b_fc1   = (const float*)d_in[15];
  const float* W_fc2   = (const float*)d_in[16];
  const float* b_fc2   = (const float*)d_in[17];
  (void)in_sizes; (void)n_in; (void)out_size; (void)ws_size;

  char* ws = (char*)d_ws;
  ushort_t* z2bf   = (ushort_t*)(ws + 0);          // 33554432
  ushort_t* wa1bf  = (ushort_t*)(ws + 33554432);   //  4194304
  ushort_t* whhbf  = (ushort_t*)(ws + 37748736);   //  8388608
  float*    z1p0   = (float*)   (ws + 46137344);   //  1048576
  float*    z1p1   = (float*)   (ws + 47185920);   //  1048576
  float*    gatesp = (float*)   (ws + 48234496);   //  4194304
  ushort_t* dsbf   = (ushort_t*)(ws + 52428800);   //  1048576
  float*    htwp   = (float*)   (ws + 54525952);   //    65536
  float*    betap  = (float*)   (ws + 54591488);   //    65536
  ushort_t* dctp   = (ushort_t*)(ws + 54657024);   //  1048576
  float*    statep = (float*)   (ws + 55705600);   //  1048576
  unsigned* bars   = (unsigned*)(ws + 56754176);   //   262144: 128 insts x 512 u32

  hipMemsetAsync(dsbf, 0, 1048576, stream);
  hipMemsetAsync(bars, 0, 262144, stream);
  cvt_k<<<dim3(256), dim3(256), 0, stream>>>(W_attn1, wa1bf, 2097152);
  cvt_k<<<dim3(256), dim3(256), 0, stream>>>(W_hh,    whhbf, 4194304);
  htw_k<<<dim3(16384), dim3(256), 0, stream>>>(h, W_tilde, htwp);
  gemm_bt_k<0><<<dim3(256, 16), dim3(256), 0, stream>>>(h, W_attn2, z2bf, b_attn1, b_attn2);

  void* kargs[] = {
    (void*)&dsbf, (void*)&wa1bf, (void*)&whhbf, (void*)&z2bf,
    (void*)&z1p0, (void*)&z1p1, (void*)&gatesp, (void*)&htwp, (void*)&W_attn3,
    (void*)&y_seq, (void*)&W_tilde, (void*)&b_tilde, (void*)&W_ih, (void*)&b_ih,
    (void*)&b_hh, (void*)&betap, (void*)&bars
  };
  hipLaunchCooperativeKernel((void*)fused_loop6_k, dim3(256), dim3(512), kargs, 0, stream);

  ct_k<<<dim3(1024), dim3(256), 0, stream>>>(h, betap, dsbf, dctp);
  gemm_bt_k<2><<<dim3(4, 16), dim3(256), 0, stream>>>(dctp, W_fc1, statep, nullptr, nullptr);
  head2_k<<<dim3(256), dim3(256), 0, stream>>>(statep, b_fc1, W_fc2, b_fc2, (float*)d_out);
}

// Round 9
// 3107.338 us; speedup vs baseline: 4.2703x; 1.3053x over previous
//
#include <hip/hip_runtime.h>

typedef unsigned short ushort_t;
typedef __attribute__((ext_vector_type(4))) float f32x4;
typedef __attribute__((ext_vector_type(8))) short s16x8;
typedef __attribute__((ext_vector_type(4))) unsigned short u16x4;
typedef __attribute__((ext_vector_type(8))) __bf16 bf16x8;

#define DEV __device__ __forceinline__

DEV float bf2f(ushort_t u){ union { unsigned int i; float f; } v; v.i = ((unsigned int)u) << 16; return v.f; }
DEV ushort_t f2bf(float f){
  union { float f; unsigned int i; } v; v.f = f;
  unsigned int r = v.i + 0x7FFFu + ((v.i >> 16) & 1u);   // RNE
  return (ushort_t)(r >> 16);
}
DEV float frcp(float x){
#if __has_builtin(__builtin_amdgcn_rcpf)
  return __builtin_amdgcn_rcpf(x);
#else
  return 1.0f / x;
#endif
}
DEV float fast_tanh(float x){
  x = fminf(9.0f, fmaxf(-9.0f, x));
  float e = __expf(2.0f * x);
  return fmaf(-2.0f, frcp(e + 1.0f), 1.0f);
}
DEV float fast_sig(float x){ return frcp(1.0f + __expf(-x)); }

DEV f32x4 mfma16(s16x8 a, s16x8 b, f32x4 c){
  return __builtin_amdgcn_mfma_f32_16x16x32_bf16(
      __builtin_bit_cast(bf16x8, a), __builtin_bit_cast(bf16x8, b), c, 0, 0, 0);
}

// Hierarchical device barrier over 256 blocks (fresh 2KB slot per use).
// Arrival: RELEASE fetch_add. Spin: RELAXED loads (no per-iter L2 inv).
// Exit: ONE ACQUIRE load -> single L2 inv per barrier. (verified r4-r8)
DEV void dbar(unsigned* inst, int g){
  __syncthreads();
  if (threadIdx.x == 0) {
    unsigned old = __hip_atomic_fetch_add(inst + g * 16, 1u, __ATOMIC_RELEASE, __HIP_MEMORY_SCOPE_AGENT);
    if (old == 31u) {
      unsigned ro = __hip_atomic_fetch_add(inst + 256, 1u, __ATOMIC_ACQ_REL, __HIP_MEMORY_SCOPE_AGENT);
      if (ro == 7u) {
        #pragma unroll
        for (int i = 0; i < 8; ++i)
          __hip_atomic_store(inst + 288 + i * 16, 1u, __ATOMIC_RELEASE, __HIP_MEMORY_SCOPE_AGENT);
      }
    }
    while (__hip_atomic_load(inst + 288 + g * 16, __ATOMIC_RELAXED, __HIP_MEMORY_SCOPE_AGENT) == 0u)
      __builtin_amdgcn_s_sleep(8);
    (void)__hip_atomic_load(inst + 288 + g * 16, __ATOMIC_ACQUIRE, __HIP_MEMORY_SCOPE_AGENT);
  }
  __syncthreads();
}

// ---------------------------------------------------------------------------
// One-shot GEMMs: C[m,n] = sum_k A[m,k]*B[n,k].
// MODE 0: A=h f32, B=W_attn2 f32 -> z2 bf16 (+b_attn1[n]+b_attn2[n])
// MODE 2: A=dct bf16 [256,2048], B=W_fc1 f32 [1024,2048] -> f32 [256,1024]
// ---------------------------------------------------------------------------
template<int MODE>
__global__ __launch_bounds__(256) void gemm_bt_k(
    const void* __restrict__ Ap, const void* __restrict__ Bp,
    void* __restrict__ Cp, const float* __restrict__ bias1, const float* __restrict__ bias2)
{
  const int bm0 = blockIdx.x * 64;
  const int bn0 = blockIdx.y * 64;
  const int tid = threadIdx.x;
  const int srow = tid >> 2, sseg = tid & 3;
  const int wid = tid >> 6, lane = tid & 63;
  const int wr = wid >> 1, wc = wid & 1;
  const int fr = lane & 15, kseg = lane >> 4;

  int K;
  const float* Af = nullptr; const ushort_t* Ab = nullptr;
  const float* Bf = nullptr;
  if constexpr (MODE == 0) {
    K = 1024;
    Af = (const float*)Ap + (size_t)(bm0 + srow) * 1024;
    Bf = (const float*)Bp + (size_t)(bn0 + srow) * 1024;
  } else {
    K = 2048;
    Ab = (const ushort_t*)Ap + (size_t)(bm0 + srow) * 2048;
    Bf = (const float*)Bp + (size_t)(bn0 + srow) * 2048;
  }

  __shared__ ushort_t As[64 * 32];
  __shared__ ushort_t Bs[64 * 32];
  f32x4 acc00 = {0,0,0,0}, acc01 = {0,0,0,0}, acc10 = {0,0,0,0}, acc11 = {0,0,0,0};

  const int sstore = srow * 32 + ((sseg ^ (srow & 3)) << 3);
  const int ar0 = wr * 32 + fr,      ar1 = wr * 32 + 16 + fr;
  const int br0 = wc * 32 + fr,      br1 = wc * 32 + 16 + fr;
  const int aoff0 = ar0 * 32 + ((kseg ^ (ar0 & 3)) << 3);
  const int aoff1 = ar1 * 32 + ((kseg ^ (ar1 & 3)) << 3);
  const int boff0 = br0 * 32 + ((kseg ^ (br0 & 3)) << 3);
  const int boff1 = br1 * 32 + ((kseg ^ (br1 & 3)) << 3);

  for (int k0 = 0; k0 < K; k0 += 32) {
    s16x8 av, bv;
    if constexpr (MODE == 0) {
      const float* p = Af + k0 + sseg * 8;
      f32x4 x0 = *(const f32x4*)p, x1 = *(const f32x4*)(p + 4);
      av[0]=(short)f2bf(x0[0]); av[1]=(short)f2bf(x0[1]); av[2]=(short)f2bf(x0[2]); av[3]=(short)f2bf(x0[3]);
      av[4]=(short)f2bf(x1[0]); av[5]=(short)f2bf(x1[1]); av[6]=(short)f2bf(x1[2]); av[7]=(short)f2bf(x1[3]);
    } else {
      av = *(const s16x8*)(Ab + k0 + sseg * 8);
    }
    {
      const float* p = Bf + k0 + sseg * 8;
      f32x4 x0 = *(const f32x4*)p, x1 = *(const f32x4*)(p + 4);
      bv[0]=(short)f2bf(x0[0]); bv[1]=(short)f2bf(x0[1]); bv[2]=(short)f2bf(x0[2]); bv[3]=(short)f2bf(x0[3]);
      bv[4]=(short)f2bf(x1[0]); bv[5]=(short)f2bf(x1[1]); bv[6]=(short)f2bf(x1[2]); bv[7]=(short)f2bf(x1[3]);
    }
    *(s16x8*)&As[sstore] = av;
    *(s16x8*)&Bs[sstore] = bv;
    __syncthreads();
    s16x8 a0 = *(const s16x8*)&As[aoff0];
    s16x8 a1 = *(const s16x8*)&As[aoff1];
    s16x8 b0 = *(const s16x8*)&Bs[boff0];
    s16x8 b1 = *(const s16x8*)&Bs[boff1];
    acc00 = mfma16(a0, b0, acc00);
    acc01 = mfma16(a0, b1, acc01);
    acc10 = mfma16(a1, b0, acc10);
    acc11 = mfma16(a1, b1, acc11);
    __syncthreads();
  }

  const int mbase = bm0 + wr * 32 + kseg * 4;
  const int nbase = bn0 + wc * 32 + fr;
  auto wr4 = [&](f32x4 v, int m0, int n0) {
    #pragma unroll
    for (int r = 0; r < 4; ++r) {
      float x = v[r];
      if constexpr (MODE == 0)
        ((ushort_t*)Cp)[(size_t)(m0 + r) * 1024 + n0] = f2bf(x + bias1[n0] + bias2[n0]);
      else
        ((float*)Cp)[(size_t)(m0 + r) * 1024 + n0] = x;
    }
  };
  wr4(acc00, mbase,      nbase);
  wr4(acc01, mbase,      nbase + 16);
  wr4(acc10, mbase + 16, nbase);
  wr4(acc11, mbase + 16, nbase + 16);
}

// ---------------------------------------------------------------------------
// Persistent recurrence. N-partitioned GEMM, LDS-resident weights, z2
// VGPR/AGPR-resident. NEW: A (dsbf) staged through LDS in 16 software-
// pipelined 32KB chunks -> ~16x more loads in flight (latency-bound fix).
// ---------------------------------------------------------------------------
__global__ __launch_bounds__(512, 2)
void fused_loop7_k(
    ushort_t* __restrict__ dsbf,
    const ushort_t* __restrict__ wa1, const ushort_t* __restrict__ whh,
    const ushort_t* __restrict__ z2bf,
    float* __restrict__ z1p0, float* __restrict__ z1p1, float* __restrict__ gates,
    const float* __restrict__ htw, const float* __restrict__ wa3,
    const float* __restrict__ y_seq, const float* __restrict__ Wt,
    const float* __restrict__ btld, const float* __restrict__ W_ih,
    const float* __restrict__ b_ih, const float* __restrict__ b_hh,
    float* __restrict__ betap, unsigned* __restrict__ bars)
{
  const int tid  = threadIdx.x;
  const int w    = tid >> 6;
  const int lane = tid & 63;
  const int fr   = lane & 15, kseg = lane >> 4;
  const int bid  = blockIdx.x;
  const int xcd  = bid & 7, r = bid >> 3;
  const int b    = bid;
  const bool ga  = (r < 24);

  __shared__ ushort_t Bs[32 * 1024];     // 64 KiB persistent B panel
  __shared__ ushort_t Astage[256 * 64];  // 32 KiB A-chunk (swizzled)
  __shared__ float wa3s[1024];           //  4 KiB
  __shared__ float wihs[4096];           // 16 KiB
  __shared__ float bsums[4096];          // 16 KiB  (b_ih + b_hh)
  __shared__ float zs[64];
  __shared__ float ys_sh[64];
  __shared__ float yt_sh;

  // ---- geometry + one-time B-panel preload ----
  int koff = 0, cld = 1024, cn0 = 0; size_t ldb = 2048;
  const ushort_t* Bsrc = wa1; float* Cd = z1p0;
  if (ga) {
    const int vbase = xcd * 768 + r * 32;
    if (vbase < 1024)      { Bsrc = wa1 + (size_t)vbase * 2048;                 koff = 0;    ldb = 2048; Cd = z1p0;  cld = 1024; cn0 = vbase; }
    else if (vbase < 2048) { Bsrc = wa1 + (size_t)(vbase - 1024) * 2048 + 1024; koff = 1024; ldb = 2048; Cd = z1p1;  cld = 1024; cn0 = vbase - 1024; }
    else                   { Bsrc = whh + (size_t)(vbase - 2048) * 1024;        koff = 0;    ldb = 1024; Cd = gates; cld = 4096; cn0 = vbase - 2048; }
    #pragma unroll
    for (int it = 0; it < 8; ++it) {
      const int p = tid + it * 512;          // 4096 x 16B chunks
      const int row = p >> 7, c = p & 127;
      s16x8 v = *(const s16x8*)(Bsrc + (size_t)row * ldb + c * 8);
      *(s16x8*)&Bs[row * 1024 + ((c ^ (row & 7)) << 3)] = v;
    }
  }
  // ---- shared small constants ----
  #pragma unroll
  for (int i = tid; i < 1024; i += 512) wa3s[i] = wa3[i];
  #pragma unroll
  for (int i = tid; i < 4096; i += 512) { wihs[i] = W_ih[i]; bsums[i] = b_ih[i] + b_hh[i]; }
  if (tid < 64) ys_sh[tid] = y_seq[b * 64 + tid];

  // ---- per-lane resident state ----
  s16x8 z2r[16];
  {
    const ushort_t* zb = z2bf + (((size_t)(b * 64 + w * 8)) << 10) + lane * 16;
    #pragma unroll
    for (int i = 0; i < 8; ++i) {
      z2r[2 * i]     = *(const s16x8*)(zb + ((size_t)i << 10));
      z2r[2 * i + 1] = *(const s16x8*)(zb + ((size_t)i << 10) + 8);
    }
  }
  const float htwv = htw[b * 64 + lane];
  const float Wt0 = Wt[0], bt0 = btld[0];
  float s0v = 0.0f, s1v = 0.0f;
  __syncthreads();

  // per-thread staging indices (4 x 16B per chunk)
  const int sp_row[4] = { (0 * 512 + tid) >> 3, (1 * 512 + tid) >> 3, (2 * 512 + tid) >> 3, (3 * 512 + tid) >> 3 };
  const int sp_ci [4] = { tid & 7, tid & 7, tid & 7, tid & 7 };   // p & 7 == tid & 7 since 512 % 8 == 0
  const int m0 = w * 32;
  const int ra0 = m0 + fr, ra1 = m0 + 16 + fr;
  const int bsw0 = fr * 1024, bsw1 = (16 + fr) * 1024, bx = fr & 7;

  for (int t = 0; t < 64; ++t) {
    // ================= GEMM phase (A chunk-staged via LDS) =================
    if (ga) {
      f32x4 acc00 = {0,0,0,0}, acc01 = {0,0,0,0}, acc10 = {0,0,0,0}, acc11 = {0,0,0,0};
      s16x8 st0, st1, st2, st3;
      {
        const ushort_t* sb = dsbf + koff;
        st0 = *(const s16x8*)(sb + (size_t)sp_row[0] * 2048 + sp_ci[0] * 8);
        st1 = *(const s16x8*)(sb + (size_t)sp_row[1] * 2048 + sp_ci[1] * 8);
        st2 = *(const s16x8*)(sb + (size_t)sp_row[2] * 2048 + sp_ci[2] * 8);
        st3 = *(const s16x8*)(sb + (size_t)sp_row[3] * 2048 + sp_ci[3] * 8);
      }
      #pragma unroll 1
      for (int kc = 0; kc < 16; ++kc) {
        *(s16x8*)&Astage[sp_row[0] * 64 + ((sp_ci[0] ^ (sp_row[0] & 7)) << 3)] = st0;
        *(s16x8*)&Astage[sp_row[1] * 64 + ((sp_ci[1] ^ (sp_row[1] & 7)) << 3)] = st1;
        *(s16x8*)&Astage[sp_row[2] * 64 + ((sp_ci[2] ^ (sp_row[2] & 7)) << 3)] = st2;
        *(s16x8*)&Astage[sp_row[3] * 64 + ((sp_ci[3] ^ (sp_row[3] & 7)) << 3)] = st3;
        __syncthreads();
        if (kc < 15) {
          const ushort_t* sb = dsbf + koff + (kc + 1) * 64;
          st0 = *(const s16x8*)(sb + (size_t)sp_row[0] * 2048 + sp_ci[0] * 8);
          st1 = *(const s16x8*)(sb + (size_t)sp_row[1] * 2048 + sp_ci[1] * 8);
          st2 = *(const s16x8*)(sb + (size_t)sp_row[2] * 2048 + sp_ci[2] * 8);
          st3 = *(const s16x8*)(sb + (size_t)sp_row[3] * 2048 + sp_ci[3] * 8);
        }
        #pragma unroll
        for (int kkk = 0; kkk < 2; ++kkk) {
          const int kk = kc * 2 + kkk;
          const int ci = kkk * 4 + kseg;
          s16x8 a0 = *(const s16x8*)&Astage[ra0 * 64 + ((ci ^ (ra0 & 7)) << 3)];
          s16x8 a1 = *(const s16x8*)&Astage[ra1 * 64 + ((ci ^ (ra1 & 7)) << 3)];
          const int sw = ((kk * 4 + kseg) ^ bx) << 3;
          s16x8 b0 = *(const s16x8*)&Bs[bsw0 + sw];
          s16x8 b1 = *(const s16x8*)&Bs[bsw1 + sw];
          acc00 = mfma16(a0, b0, acc00);
          acc01 = mfma16(a0, b1, acc01);
          acc10 = mfma16(a1, b0, acc10);
          acc11 = mfma16(a1, b1, acc11);
        }
        __syncthreads();
      }
      const int orow = m0 + kseg * 4;
      const int ocol = cn0 + fr;
      #pragma unroll
      for (int ri = 0; ri < 4; ++ri) {
        Cd[(size_t)(orow + ri)      * cld + ocol]      = acc00[ri];
        Cd[(size_t)(orow + ri)      * cld + ocol + 16] = acc01[ri];
        Cd[(size_t)(orow + ri + 16) * cld + ocol]      = acc10[ri];
        Cd[(size_t)(orow + ri + 16) * cld + ocol + 16] = acc11[ri];
      }
    }
    dbar(bars + (size_t)(t * 2) * 512, xcd);

    // ---- prefetch this step's gate pre-activations ----
    float gp0 = 0, gp1 = 0, gp2 = 0, gp3 = 0, gp4 = 0, gp5 = 0, gp6 = 0, gp7 = 0;
    if (t < 63) {
      const float* gb = gates + (size_t)b * 4096;
      gp0 = gb[tid];        gp1 = gb[1024 + tid];
      gp2 = gb[2048 + tid]; gp3 = gb[3072 + tid];
      gp4 = gb[512 + tid];  gp5 = gb[1536 + tid];
      gp6 = gb[2560 + tid]; gp7 = gb[3584 + tid];
    }

    // ================= attention phase (batch b = bid) =================
    float z1c[16], wc3[16];
    {
      const float* zp0 = z1p0 + (size_t)b * 1024 + lane * 16;
      const float* zp1 = z1p1 + (size_t)b * 1024 + lane * 16;
      #pragma unroll
      for (int q = 0; q < 16; q += 4) {
        f32x4 a0 = *(const f32x4*)(zp0 + q);
        f32x4 a1 = *(const f32x4*)(zp1 + q);
        f32x4 c  = *(const f32x4*)(&wa3s[lane * 16 + q]);
        z1c[q]   = a0[0] + a1[0]; z1c[q+1] = a0[1] + a1[1];
        z1c[q+2] = a0[2] + a1[2]; z1c[q+3] = a0[3] + a1[3];
        wc3[q] = c[0]; wc3[q+1] = c[1]; wc3[q+2] = c[2]; wc3[q+3] = c[3];
      }
    }
    #pragma unroll
    for (int i = 0; i < 8; ++i) {
      s16x8 v0 = z2r[2 * i];
      s16x8 v1 = z2r[2 * i + 1];
      float acc = 0.0f;
      #pragma unroll
      for (int q = 0; q < 8; ++q) acc = fmaf(fast_tanh(z1c[q]     + bf2f((ushort_t)v0[q])), wc3[q],     acc);
      #pragma unroll
      for (int q = 0; q < 8; ++q) acc = fmaf(fast_tanh(z1c[8 + q] + bf2f((ushort_t)v1[q])), wc3[8 + q], acc);
      #pragma unroll
      for (int m = 32; m >= 1; m >>= 1) acc += __shfl_xor(acc, m);
      if (lane == 0) zs[w * 8 + i] = acc;
    }
    __syncthreads();

    if (w == 0) {
      float v = zs[lane];
      float mx = v;
      #pragma unroll
      for (int m = 32; m >= 1; m >>= 1) mx = fmaxf(mx, __shfl_xor(mx, m));
      float e = __expf(v - mx);
      float sum = e;
      #pragma unroll
      for (int m = 32; m >= 1; m >>= 1) sum += __shfl_xor(sum, m);
      float betav = e * frcp(sum);
      if (t == 63) betap[b * 64 + lane] = betav;
      float a = betav * htwv;
      #pragma unroll
      for (int m = 32; m >= 1; m >>= 1) a += __shfl_xor(a, m);
      if (lane == 0) yt_sh = fmaf(Wt0, ys_sh[t], a + bt0);
    }
    __syncthreads();

    if (t < 63) {
      const float ytv = yt_sh;
      {
        float gi = gp0 + ytv * wihs[tid]        + bsums[tid];
        float gf = gp1 + ytv * wihs[1024 + tid] + bsums[1024 + tid];
        float gg = gp2 + ytv * wihs[2048 + tid] + bsums[2048 + tid];
        float go = gp3 + ytv * wihs[3072 + tid] + bsums[3072 + tid];
        float ig = fast_sig(gi), fg = fast_sig(gf), gt = fast_tanh(gg), og = fast_sig(go);
        float sn = fmaf(fg, s0v, ig * gt);
        float dn = og * fast_tanh(sn);
        s0v = sn;
        dsbf[(size_t)b * 2048 + tid] = f2bf(dn);
        dsbf[(size_t)b * 2048 + 1024 + tid] = f2bf(sn);
      }
      {
        const int hi = tid + 512;
        float gi = gp4 + ytv * wihs[hi]        + bsums[hi];
        float gf = gp5 + ytv * wihs[1024 + hi] + bsums[1024 + hi];
        float gg = gp6 + ytv * wihs[2048 + hi] + bsums[2048 + hi];
        float go = gp7 + ytv * wihs[3072 + hi] + bsums[3072 + hi];
        float ig = fast_sig(gi), fg = fast_sig(gf), gt = fast_tanh(gg), og = fast_sig(go);
        float sn = fmaf(fg, s1v, ig * gt);
        float dn = og * fast_tanh(sn);
        s1v = sn;
        dsbf[(size_t)b * 2048 + hi] = f2bf(dn);
        dsbf[(size_t)b * 2048 + 1024 + hi] = f2bf(sn);
      }
      dbar(bars + (size_t)(t * 2 + 1) * 512, xcd);
    }
  }
}

// htw[b,t] = sum_c h[b,t,c] * W_tilde[1+c]
__global__ __launch_bounds__(256) void htw_k(const float* __restrict__ h, const float* __restrict__ Wt,
                                             float* __restrict__ htw)
{
  const int btx = blockIdx.x;
  const int tid = threadIdx.x;
  const float* hp = h + ((size_t)btx << 10);
  const int c = tid * 4;
  f32x4 hv = *(const f32x4*)(hp + c);
  float acc = hv[0]*Wt[1+c] + hv[1]*Wt[2+c] + hv[2]*Wt[3+c] + hv[3]*Wt[4+c];
  #pragma unroll
  for (int m = 32; m >= 1; m >>= 1) acc += __shfl_xor(acc, m);
  __shared__ float red[4];
  if ((tid & 63) == 0) red[tid >> 6] = acc;
  __syncthreads();
  if (tid == 0) htw[btx] = red[0] + red[1] + red[2] + red[3];
}

// ct[b,c] = sum_t beta[b,t]*h[b,t,c]; assemble dct = [d | ct] bf16
__global__ __launch_bounds__(256) void ct_k(const float* __restrict__ h, const float* __restrict__ beta,
                                            const ushort_t* __restrict__ ds_bf, ushort_t* __restrict__ dct)
{
  const int bid = blockIdx.x;
  const int b = bid >> 2, cb = bid & 3;
  const int c = cb * 256 + threadIdx.x;
  const float* hp = h + ((size_t)b << 16) + c;
  const float* bp = beta + b * 64;
  float acc = 0.0f;
  #pragma unroll 8
  for (int t = 0; t < 64; ++t) acc = fmaf(bp[t], hp[(size_t)t << 10], acc);
  dct[(size_t)b * 2048 + 1024 + c] = f2bf(acc);
  dct[(size_t)b * 2048 + c] = ds_bf[(size_t)b * 2048 + c];
}

// y[b] = sum_n (state[b,n]+b_fc1[n]) * W_fc2[n] + b_fc2   (f32 output)
__global__ __launch_bounds__(256) void head2_k(const float* __restrict__ state, const float* __restrict__ b_fc1,
                                               const float* __restrict__ W_fc2, const float* __restrict__ b_fc2,
                                               float* __restrict__ out)
{
  const int b = blockIdx.x, tid = threadIdx.x;
  const int c = tid * 4;
  f32x4 sv = *(const f32x4*)(state + ((size_t)b << 10) + c);
  f32x4 bv = *(const f32x4*)(b_fc1 + c);
  f32x4 wv = *(const f32x4*)(W_fc2 + c);
  float acc = (sv[0]+bv[0])*wv[0] + (sv[1]+bv[1])*wv[1] + (sv[2]+bv[2])*wv[2] + (sv[3]+bv[3])*wv[3];
  #pragma unroll
  for (int m = 32; m >= 1; m >>= 1) acc += __shfl_xor(acc, m);
  __shared__ float red[4];
  if ((tid & 63) == 0) red[tid >> 6] = acc;
  __syncthreads();
  if (tid == 0) out[b] = red[0] + red[1] + red[2] + red[3] + b_fc2[0];
}

__global__ void cvt_k(const float* __restrict__ in, ushort_t* __restrict__ out, int n)
{
  int i = (blockIdx.x * blockDim.x + threadIdx.x) * 4;
  const int stride = gridDim.x * blockDim.x * 4;
  for (; i < n; i += stride) {
    f32x4 v = *(const f32x4*)(in + i);
    u16x4 o; o[0] = f2bf(v[0]); o[1] = f2bf(v[1]); o[2] = f2bf(v[2]); o[3] = f2bf(v[3]);
    *(u16x4*)(out + i) = o;
  }
}

extern "C" void kernel_launch(void* const* d_in, const int* in_sizes, int n_in,
                              void* d_out, int out_size, void* d_ws, size_t ws_size,
                              hipStream_t stream)
{
  const float* h       = (const float*)d_in[0];
  const float* y_seq   = (const float*)d_in[1];
  const float* W_attn1 = (const float*)d_in[2];
  const float* b_attn1 = (const float*)d_in[3];
  const float* W_attn2 = (const float*)d_in[4];
  const float* b_attn2 = (const float*)d_in[5];
  const float* W_attn3 = (const float*)d_in[6];
  // d_in[7] = b_attn3: softmax shift-invariant, unused
  const float* W_ih    = (const float*)d_in[8];
  const float* W_hh    = (const float*)d_in[9];
  const float* b_ih    = (const float*)d_in[10];
  const float* b_hh    = (const float*)d_in[11];
  const float* W_tilde = (const float*)d_in[12];
  const float* b_tilde = (const float*)d_in[13];
  const float* W_fc1   = (const float*)d_in[14];
  const float* b_fc1   = (const float*)d_in[15];
  const float* W_fc2   = (const float*)d_in[16];
  const float* b_fc2   = (const float*)d_in[17];
  (void)in_sizes; (void)n_in; (void)out_size; (void)ws_size;

  char* ws = (char*)d_ws;
  ushort_t* z2bf   = (ushort_t*)(ws + 0);          // 33554432
  ushort_t* wa1bf  = (ushort_t*)(ws + 33554432);   //  4194304
  ushort_t* whhbf  = (ushort_t*)(ws + 37748736);   //  8388608
  float*    z1p0   = (float*)   (ws + 46137344);   //  1048576
  float*    z1p1   = (float*)   (ws + 47185920);   //  1048576
  float*    gatesp = (float*)   (ws + 48234496);   //  4194304
  ushort_t* dsbf   = (ushort_t*)(ws + 52428800);   //  1048576
  float*    htwp   = (float*)   (ws + 54525952);   //    65536
  float*    betap  = (float*)   (ws + 54591488);   //    65536
  ushort_t* dctp   = (ushort_t*)(ws + 54657024);   //  1048576
  float*    statep = (float*)   (ws + 55705600);   //  1048576
  unsigned* bars   = (unsigned*)(ws + 56754176);   //   262144: 128 insts x 512 u32

  hipMemsetAsync(dsbf, 0, 1048576, stream);
  hipMemsetAsync(bars, 0, 262144, stream);
  cvt_k<<<dim3(256), dim3(256), 0, stream>>>(W_attn1, wa1bf, 2097152);
  cvt_k<<<dim3(256), dim3(256), 0, stream>>>(W_hh,    whhbf, 4194304);
  htw_k<<<dim3(16384), dim3(256), 0, stream>>>(h, W_tilde, htwp);
  gemm_bt_k<0><<<dim3(256, 16), dim3(256), 0, stream>>>(h, W_attn2, z2bf, b_attn1, b_attn2);

  void* kargs[] = {
    (void*)&dsbf, (void*)&wa1bf, (void*)&whhbf, (void*)&z2bf,
    (void*)&z1p0, (void*)&z1p1, (void*)&gatesp, (void*)&htwp, (void*)&W_attn3,
    (void*)&y_seq, (void*)&W_tilde, (void*)&b_tilde, (void*)&W_ih, (void*)&b_ih,
    (void*)&b_hh, (void*)&betap, (void*)&bars
  };
  hipLaunchCooperativeKernel((void*)fused_loop7_k, dim3(256), dim3(512), kargs, 0, stream);

  ct_k<<<dim3(1024), dim3(256), 0, stream>>>(h, betap, dsbf, dctp);
  gemm_bt_k<2><<<dim3(4, 16), dim3(256), 0, stream>>>(dctp, W_fc1, statep, nullptr, nullptr);
  head2_k<<<dim3(256), dim3(256), 0, stream>>>(statep, b_fc1, W_fc2, b_fc2, (float*)d_out);
}

// Round 10
// 3072.829 us; speedup vs baseline: 4.3183x; 1.0112x over previous
//
#include <hip/hip_runtime.h>

typedef unsigned short ushort_t;
typedef __attribute__((ext_vector_type(4))) float f32x4;
typedef __attribute__((ext_vector_type(8))) short s16x8;
typedef __attribute__((ext_vector_type(4))) unsigned short u16x4;
typedef __attribute__((ext_vector_type(8))) __bf16 bf16x8;

#define DEV __device__ __forceinline__

DEV float bf2f(ushort_t u){ union { unsigned int i; float f; } v; v.i = ((unsigned int)u) << 16; return v.f; }
DEV ushort_t f2bf(float f){
  union { float f; unsigned int i; } v; v.f = f;
  unsigned int r = v.i + 0x7FFFu + ((v.i >> 16) & 1u);   // RNE
  return (ushort_t)(r >> 16);
}
DEV float frcp(float x){
#if __has_builtin(__builtin_amdgcn_rcpf)
  return __builtin_amdgcn_rcpf(x);
#else
  return 1.0f / x;
#endif
}
DEV float fast_tanh(float x){
  x = fminf(9.0f, fmaxf(-9.0f, x));
  float e = __expf(2.0f * x);
  return fmaf(-2.0f, frcp(e + 1.0f), 1.0f);
}
DEV float fast_sig(float x){ return frcp(1.0f + __expf(-x)); }

DEV f32x4 mfma16(s16x8 a, s16x8 b, f32x4 c){
  return __builtin_amdgcn_mfma_f32_16x16x32_bf16(
      __builtin_bit_cast(bf16x8, a), __builtin_bit_cast(bf16x8, b), c, 0, 0, 0);
}

// Hierarchical device barrier over 256 blocks (fresh 2KB slot per use).
// Arrival: RELEASE fetch_add. Spin: RELAXED loads. Exit: ONE ACQUIRE load.
// (mechanism verified r4-r9)
DEV void dbar(unsigned* inst, int g){
  __syncthreads();
  if (threadIdx.x == 0) {
    unsigned old = __hip_atomic_fetch_add(inst + g * 16, 1u, __ATOMIC_RELEASE, __HIP_MEMORY_SCOPE_AGENT);
    if (old == 31u) {
      unsigned ro = __hip_atomic_fetch_add(inst + 256, 1u, __ATOMIC_ACQ_REL, __HIP_MEMORY_SCOPE_AGENT);
      if (ro == 7u) {
        #pragma unroll
        for (int i = 0; i < 8; ++i)
          __hip_atomic_store(inst + 288 + i * 16, 1u, __ATOMIC_RELEASE, __HIP_MEMORY_SCOPE_AGENT);
      }
    }
    while (__hip_atomic_load(inst + 288 + g * 16, __ATOMIC_RELAXED, __HIP_MEMORY_SCOPE_AGENT) == 0u)
      __builtin_amdgcn_s_sleep(1);
    (void)__hip_atomic_load(inst + 288 + g * 16, __ATOMIC_ACQUIRE, __HIP_MEMORY_SCOPE_AGENT);
  }
  __syncthreads();
}

// ---------------------------------------------------------------------------
// One-shot GEMMs: C[m,n] = sum_k A[m,k]*B[n,k].
// MODE 0: A=h f32, B=W_attn2 f32 -> z2 bf16 (+b_attn1[n]+b_attn2[n])
// MODE 2: A=dct bf16 [256,2048], B=W_fc1 f32 [1024,2048] -> f32 [256,1024]
// ---------------------------------------------------------------------------
template<int MODE>
__global__ __launch_bounds__(256) void gemm_bt_k(
    const void* __restrict__ Ap, const void* __restrict__ Bp,
    void* __restrict__ Cp, const float* __restrict__ bias1, const float* __restrict__ bias2)
{
  const int bm0 = blockIdx.x * 64;
  const int bn0 = blockIdx.y * 64;
  const int tid = threadIdx.x;
  const int srow = tid >> 2, sseg = tid & 3;
  const int wid = tid >> 6, lane = tid & 63;
  const int wr = wid >> 1, wc = wid & 1;
  const int fr = lane & 15, kseg = lane >> 4;

  int K;
  const float* Af = nullptr; const ushort_t* Ab = nullptr;
  const float* Bf = nullptr;
  if constexpr (MODE == 0) {
    K = 1024;
    Af = (const float*)Ap + (size_t)(bm0 + srow) * 1024;
    Bf = (const float*)Bp + (size_t)(bn0 + srow) * 1024;
  } else {
    K = 2048;
    Ab = (const ushort_t*)Ap + (size_t)(bm0 + srow) * 2048;
    Bf = (const float*)Bp + (size_t)(bn0 + srow) * 2048;
  }

  __shared__ ushort_t As[64 * 32];
  __shared__ ushort_t Bs[64 * 32];
  f32x4 acc00 = {0,0,0,0}, acc01 = {0,0,0,0}, acc10 = {0,0,0,0}, acc11 = {0,0,0,0};

  const int sstore = srow * 32 + ((sseg ^ (srow & 3)) << 3);
  const int ar0 = wr * 32 + fr,      ar1 = wr * 32 + 16 + fr;
  const int br0 = wc * 32 + fr,      br1 = wc * 32 + 16 + fr;
  const int aoff0 = ar0 * 32 + ((kseg ^ (ar0 & 3)) << 3);
  const int aoff1 = ar1 * 32 + ((kseg ^ (ar1 & 3)) << 3);
  const int boff0 = br0 * 32 + ((kseg ^ (br0 & 3)) << 3);
  const int boff1 = br1 * 32 + ((kseg ^ (br1 & 3)) << 3);

  for (int k0 = 0; k0 < K; k0 += 32) {
    s16x8 av, bv;
    if constexpr (MODE == 0) {
      const float* p = Af + k0 + sseg * 8;
      f32x4 x0 = *(const f32x4*)p, x1 = *(const f32x4*)(p + 4);
      av[0]=(short)f2bf(x0[0]); av[1]=(short)f2bf(x0[1]); av[2]=(short)f2bf(x0[2]); av[3]=(short)f2bf(x0[3]);
      av[4]=(short)f2bf(x1[0]); av[5]=(short)f2bf(x1[1]); av[6]=(short)f2bf(x1[2]); av[7]=(short)f2bf(x1[3]);
    } else {
      av = *(const s16x8*)(Ab + k0 + sseg * 8);
    }
    {
      const float* p = Bf + k0 + sseg * 8;
      f32x4 x0 = *(const f32x4*)p, x1 = *(const f32x4*)(p + 4);
      bv[0]=(short)f2bf(x0[0]); bv[1]=(short)f2bf(x0[1]); bv[2]=(short)f2bf(x0[2]); bv[3]=(short)f2bf(x0[3]);
      bv[4]=(short)f2bf(x1[0]); bv[5]=(short)f2bf(x1[1]); bv[6]=(short)f2bf(x1[2]); bv[7]=(short)f2bf(x1[3]);
    }
    *(s16x8*)&As[sstore] = av;
    *(s16x8*)&Bs[sstore] = bv;
    __syncthreads();
    s16x8 a0 = *(const s16x8*)&As[aoff0];
    s16x8 a1 = *(const s16x8*)&As[aoff1];
    s16x8 b0 = *(const s16x8*)&Bs[boff0];
    s16x8 b1 = *(const s16x8*)&Bs[boff1];
    acc00 = mfma16(a0, b0, acc00);
    acc01 = mfma16(a0, b1, acc01);
    acc10 = mfma16(a1, b0, acc10);
    acc11 = mfma16(a1, b1, acc11);
    __syncthreads();
  }

  const int mbase = bm0 + wr * 32 + kseg * 4;
  const int nbase = bn0 + wc * 32 + fr;
  auto wr4 = [&](f32x4 v, int m0, int n0) {
    #pragma unroll
    for (int r = 0; r < 4; ++r) {
      float x = v[r];
      if constexpr (MODE == 0)
        ((ushort_t*)Cp)[(size_t)(m0 + r) * 1024 + n0] = f2bf(x + bias1[n0] + bias2[n0]);
      else
        ((float*)Cp)[(size_t)(m0 + r) * 1024 + n0] = x;
    }
  };
  wr4(acc00, mbase,      nbase);
  wr4(acc01, mbase,      nbase + 16);
  wr4(acc10, mbase + 16, nbase);
  wr4(acc11, mbase + 16, nbase + 16);
}

// ---------------------------------------------------------------------------
// Persistent recurrence. N-partitioned GEMM, LDS-resident weights, z2
// VGPR/AGPR-resident. Round-10: (1) z1/gates exchanged as bf16 (halve
// cross-XCD bytes); (2) A-staging double-buffered 16KB chunks, loads 3
// chunks ahead (triple reg set, full unroll); (3) post-bar1 prefetch of
// z1+gates; (4) s_sleep(1) in dbar.
// ---------------------------------------------------------------------------
__global__ __launch_bounds__(512, 2)
void fused_loop8_k(
    ushort_t* __restrict__ dsbf,
    const ushort_t* __restrict__ wa1, const ushort_t* __restrict__ whh,
    const ushort_t* __restrict__ z2bf,
    ushort_t* __restrict__ z1p0, ushort_t* __restrict__ z1p1, ushort_t* __restrict__ gates,
    const float* __restrict__ htw, const float* __restrict__ wa3,
    const float* __restrict__ y_seq, const float* __restrict__ Wt,
    const float* __restrict__ btld, const float* __restrict__ W_ih,
    const float* __restrict__ b_ih, const float* __restrict__ b_hh,
    float* __restrict__ betap, unsigned* __restrict__ bars)
{
  const int tid  = threadIdx.x;
  const int w    = tid >> 6;
  const int lane = tid & 63;
  const int fr   = lane & 15, kseg = lane >> 4;
  const int bid  = blockIdx.x;
  const int xcd  = bid & 7, r = bid >> 3;
  const int b    = bid;
  const bool ga  = (r < 24);

  __shared__ ushort_t Bs[32 * 1024];      // 64 KiB persistent B panel
  __shared__ ushort_t Astage[2 * 8192];   // 32 KiB: 2 x (256 rows x 32 k) chunks
  __shared__ float wa3s[1024];            //  4 KiB
  __shared__ float wihs[4096];            // 16 KiB
  __shared__ float bsums[4096];           // 16 KiB  (b_ih + b_hh)
  __shared__ float zs[64];
  __shared__ float ys_sh[64];
  __shared__ float yt_sh;

  // ---- geometry + one-time B-panel preload ----
  int koff = 0, cld = 1024, cn0 = 0; size_t ldb = 2048;
  const ushort_t* Bsrc = wa1; ushort_t* Cd = z1p0;
  if (ga) {
    const int vbase = xcd * 768 + r * 32;
    if (vbase < 1024)      { Bsrc = wa1 + (size_t)vbase * 2048;                 koff = 0;    ldb = 2048; Cd = z1p0;  cld = 1024; cn0 = vbase; }
    else if (vbase < 2048) { Bsrc = wa1 + (size_t)(vbase - 1024) * 2048 + 1024; koff = 1024; ldb = 2048; Cd = z1p1;  cld = 1024; cn0 = vbase - 1024; }
    else                   { Bsrc = whh + (size_t)(vbase - 2048) * 1024;        koff = 0;    ldb = 1024; Cd = gates; cld = 4096; cn0 = vbase - 2048; }
    #pragma unroll
    for (int it = 0; it < 8; ++it) {
      const int p = tid + it * 512;          // 4096 x 16B chunks
      const int row = p >> 7, c = p & 127;
      s16x8 v = *(const s16x8*)(Bsrc + (size_t)row * ldb + c * 8);
      *(s16x8*)&Bs[row * 1024 + ((c ^ (row & 7)) << 3)] = v;
    }
  }
  // ---- shared small constants ----
  #pragma unroll
  for (int i = tid; i < 1024; i += 512) wa3s[i] = wa3[i];
  #pragma unroll
  for (int i = tid; i < 4096; i += 512) { wihs[i] = W_ih[i]; bsums[i] = b_ih[i] + b_hh[i]; }
  if (tid < 64) ys_sh[tid] = y_seq[b * 64 + tid];

  // ---- per-lane resident state ----
  s16x8 z2r[16];
  {
    const ushort_t* zb = z2bf + (((size_t)(b * 64 + w * 8)) << 10) + lane * 16;
    #pragma unroll
    for (int i = 0; i < 8; ++i) {
      z2r[2 * i]     = *(const s16x8*)(zb + ((size_t)i << 10));
      z2r[2 * i + 1] = *(const s16x8*)(zb + ((size_t)i << 10) + 8);
    }
  }
  const float htwv = htw[b * 64 + lane];
  const float Wt0 = Wt[0], bt0 = btld[0];
  float s0v = 0.0f, s1v = 0.0f;
  __syncthreads();

  // ---- staging geometry: chunk = 256 rows x 32 k (16 KiB), 2/thread ----
  const int rowA = tid >> 2, rowB = rowA + 128, ci = tid & 3;
  const int laoff = rowA * 32 + ((ci ^ (rowA & 3)) << 3);
  const int lboff = rowB * 32 + ((ci ^ (rowB & 3)) << 3);
  const int m0 = w * 32;
  const int asw = fr & 3;
  const int arow0 = (m0 + fr) * 32, arow1 = (m0 + 16 + fr) * 32;
  const int aoffk = (kseg ^ asw) << 3;
  const int bsw0 = fr * 1024, bsw1 = (16 + fr) * 1024, bx = fr & 7;

  for (int t = 0; t < 64; ++t) {
    // ================= GEMM phase =================
    if (ga) {
      f32x4 acc00 = {0,0,0,0}, acc01 = {0,0,0,0}, acc10 = {0,0,0,0}, acc11 = {0,0,0,0};
      s16x8 RA[3], RB[3];
      #pragma unroll
      for (int j = 0; j < 3; ++j) {
        const ushort_t* g = dsbf + koff + j * 32 + ci * 8;
        RA[j] = *(const s16x8*)(g + (size_t)rowA * 2048);
        RB[j] = *(const s16x8*)(g + (size_t)rowB * 2048);
      }
      *(s16x8*)&Astage[laoff] = RA[0];
      *(s16x8*)&Astage[lboff] = RB[0];
      __syncthreads();
      #pragma unroll
      for (int kc = 0; kc < 32; ++kc) {
        if (kc < 31) {
          const int bo = ((kc + 1) & 1) * 8192;
          *(s16x8*)&Astage[bo + laoff] = RA[(kc + 1) % 3];
          *(s16x8*)&Astage[bo + lboff] = RB[(kc + 1) % 3];
        }
        const int bufo = (kc & 1) * 8192;
        s16x8 a0 = *(const s16x8*)&Astage[bufo + arow0 + aoffk];
        s16x8 a1 = *(const s16x8*)&Astage[bufo + arow1 + aoffk];
        const int sw = ((kc * 4 + kseg) ^ bx) << 3;
        s16x8 b0 = *(const s16x8*)&Bs[bsw0 + sw];
        s16x8 b1 = *(const s16x8*)&Bs[bsw1 + sw];
        acc00 = mfma16(a0, b0, acc00);
        acc01 = mfma16(a0, b1, acc01);
        acc10 = mfma16(a1, b0, acc10);
        acc11 = mfma16(a1, b1, acc11);
        __syncthreads();
        if (kc + 3 < 32) {
          const ushort_t* g = dsbf + koff + (kc + 3) * 32 + ci * 8;
          RA[kc % 3] = *(const s16x8*)(g + (size_t)rowA * 2048);
          RB[kc % 3] = *(const s16x8*)(g + (size_t)rowB * 2048);
        }
      }
      const int orow = m0 + kseg * 4;
      const int ocol = cn0 + fr;
      #pragma unroll
      for (int ri = 0; ri < 4; ++ri) {
        Cd[(size_t)(orow + ri)      * cld + ocol]      = f2bf(acc00[ri]);
        Cd[(size_t)(orow + ri)      * cld + ocol + 16] = f2bf(acc01[ri]);
        Cd[(size_t)(orow + ri + 16) * cld + ocol]      = f2bf(acc10[ri]);
        Cd[(size_t)(orow + ri + 16) * cld + ocol + 16] = f2bf(acc11[ri]);
      }
    }
    dbar(bars + (size_t)(t * 2) * 512, xcd);

    // ---- prefetch: gates (8 x bf16) + z1 (4 x 16B) back-to-back ----
    ushort_t g0 = 0, g1 = 0, g2 = 0, g3 = 0, g4 = 0, g5 = 0, g6 = 0, g7 = 0;
    if (t < 63) {
      const ushort_t* gb = gates + (size_t)b * 4096;
      g0 = gb[tid];        g1 = gb[1024 + tid];
      g2 = gb[2048 + tid]; g3 = gb[3072 + tid];
      g4 = gb[512 + tid];  g5 = gb[1536 + tid];
      g6 = gb[2560 + tid]; g7 = gb[3584 + tid];
    }
    s16x8 z10a, z10b, z11a, z11b;
    {
      const ushort_t* zp0 = z1p0 + (size_t)b * 1024 + lane * 16;
      const ushort_t* zp1 = z1p1 + (size_t)b * 1024 + lane * 16;
      z10a = *(const s16x8*)zp0; z10b = *(const s16x8*)(zp0 + 8);
      z11a = *(const s16x8*)zp1; z11b = *(const s16x8*)(zp1 + 8);
    }

    // ================= attention phase (batch b = bid) =================
    float z1c[16], wc3[16];
    #pragma unroll
    for (int q = 0; q < 8; ++q) {
      z1c[q]     = bf2f((ushort_t)z10a[q]) + bf2f((ushort_t)z11a[q]);
      z1c[8 + q] = bf2f((ushort_t)z10b[q]) + bf2f((ushort_t)z11b[q]);
    }
    #pragma unroll
    for (int q = 0; q < 16; q += 4) {
      f32x4 c = *(const f32x4*)(&wa3s[lane * 16 + q]);
      wc3[q] = c[0]; wc3[q+1] = c[1]; wc3[q+2] = c[2]; wc3[q+3] = c[3];
    }
    #pragma unroll
    for (int i = 0; i < 8; ++i) {
      s16x8 v0 = z2r[2 * i];
      s16x8 v1 = z2r[2 * i + 1];
      float acc = 0.0f;
      #pragma unroll
      for (int q = 0; q < 8; ++q) acc = fmaf(fast_tanh(z1c[q]     + bf2f((ushort_t)v0[q])), wc3[q],     acc);
      #pragma unroll
      for (int q = 0; q < 8; ++q) acc = fmaf(fast_tanh(z1c[8 + q] + bf2f((ushort_t)v1[q])), wc3[8 + q], acc);
      #pragma unroll
      for (int m = 32; m >= 1; m >>= 1) acc += __shfl_xor(acc, m);
      if (lane == 0) zs[w * 8 + i] = acc;
    }
    __syncthreads();

    if (w == 0) {
      float v = zs[lane];
      float mx = v;
      #pragma unroll
      for (int m = 32; m >= 1; m >>= 1) mx = fmaxf(mx, __shfl_xor(mx, m));
      float e = __expf(v - mx);
      float sum = e;
      #pragma unroll
      for (int m = 32; m >= 1; m >>= 1) sum += __shfl_xor(sum, m);
      float betav = e * frcp(sum);
      if (t == 63) betap[b * 64 + lane] = betav;
      float a = betav * htwv;
      #pragma unroll
      for (int m = 32; m >= 1; m >>= 1) a += __shfl_xor(a, m);
      if (lane == 0) yt_sh = fmaf(Wt0, ys_sh[t], a + bt0);
    }
    __syncthreads();

    if (t < 63) {
      const float ytv = yt_sh;
      {
        float gi = bf2f(g0) + ytv * wihs[tid]        + bsums[tid];
        float gf = bf2f(g1) + ytv * wihs[1024 + tid] + bsums[1024 + tid];
        float gg = bf2f(g2) + ytv * wihs[2048 + tid] + bsums[2048 + tid];
        float go = bf2f(g3) + ytv * wihs[3072 + tid] + bsums[3072 + tid];
        float ig = fast_sig(gi), fg = fast_sig(gf), gt = fast_tanh(gg), og = fast_sig(go);
        float sn = fmaf(fg, s0v, ig * gt);
        float dn = og * fast_tanh(sn);
        s0v = sn;
        dsbf[(size_t)b * 2048 + tid] = f2bf(dn);
        dsbf[(size_t)b * 2048 + 1024 + tid] = f2bf(sn);
      }
      {
        const int hi = tid + 512;
        float gi = bf2f(g4) + ytv * wihs[hi]        + bsums[hi];
        float gf = bf2f(g5) + ytv * wihs[1024 + hi] + bsums[1024 + hi];
        float gg = bf2f(g6) + ytv * wihs[2048 + hi] + bsums[2048 + hi];
        float go = bf2f(g7) + ytv * wihs[3072 + hi] + bsums[3072 + hi];
        float ig = fast_sig(gi), fg = fast_sig(gf), gt = fast_tanh(gg), og = fast_sig(go);
        float sn = fmaf(fg, s1v, ig * gt);
        float dn = og * fast_tanh(sn);
        s1v = sn;
        dsbf[(size_t)b * 2048 + hi] = f2bf(dn);
        dsbf[(size_t)b * 2048 + 1024 + hi] = f2bf(sn);
      }
      dbar(bars + (size_t)(t * 2 + 1) * 512, xcd);
    }
  }
}

// htw[b,t] = sum_c h[b,t,c] * W_tilde[1+c]
__global__ __launch_bounds__(256) void htw_k(const float* __restrict__ h, const float* __restrict__ Wt,
                                             float* __restrict__ htw)
{
  const int btx = blockIdx.x;
  const int tid = threadIdx.x;
  const float* hp = h + ((size_t)btx << 10);
  const int c = tid * 4;
  f32x4 hv = *(const f32x4*)(hp + c);
  float acc = hv[0]*Wt[1+c] + hv[1]*Wt[2+c] + hv[2]*Wt[3+c] + hv[3]*Wt[4+c];
  #pragma unroll
  for (int m = 32; m >= 1; m >>= 1) acc += __shfl_xor(acc, m);
  __shared__ float red[4];
  if ((tid & 63) == 0) red[tid >> 6] = acc;
  __syncthreads();
  if (tid == 0) htw[btx] = red[0] + red[1] + red[2] + red[3];
}

// ct[b,c] = sum_t beta[b,t]*h[b,t,c]; assemble dct = [d | ct] bf16
__global__ __launch_bounds__(256) void ct_k(const float* __restrict__ h, const float* __restrict__ beta,
                                            const ushort_t* __restrict__ ds_bf, ushort_t* __restrict__ dct)
{
  const int bid = blockIdx.x;
  const int b = bid >> 2, cb = bid & 3;
  const int c = cb * 256 + threadIdx.x;
  const float* hp = h + ((size_t)b << 16) + c;
  const float* bp = beta + b * 64;
  float acc = 0.0f;
  #pragma unroll 8
  for (int t = 0; t < 64; ++t) acc = fmaf(bp[t], hp[(size_t)t << 10], acc);
  dct[(size_t)b * 2048 + 1024 + c] = f2bf(acc);
  dct[(size_t)b * 2048 + c] = ds_bf[(size_t)b * 2048 + c];
}

// y[b] = sum_n (state[b,n]+b_fc1[n]) * W_fc2[n] + b_fc2   (f32 output)
__global__ __launch_bounds__(256) void head2_k(const float* __restrict__ state, const float* __restrict__ b_fc1,
                                               const float* __restrict__ W_fc2, const float* __restrict__ b_fc2,
                                               float* __restrict__ out)
{
  const int b = blockIdx.x, tid = threadIdx.x;
  const int c = tid * 4;
  f32x4 sv = *(const f32x4*)(state + ((size_t)b << 10) + c);
  f32x4 bv = *(const f32x4*)(b_fc1 + c);
  f32x4 wv = *(const f32x4*)(W_fc2 + c);
  float acc = (sv[0]+bv[0])*wv[0] + (sv[1]+bv[1])*wv[1] + (sv[2]+bv[2])*wv[2] + (sv[3]+bv[3])*wv[3];
  #pragma unroll
  for (int m = 32; m >= 1; m >>= 1) acc += __shfl_xor(acc, m);
  __shared__ float red[4];
  if ((tid & 63) == 0) red[tid >> 6] = acc;
  __syncthreads();
  if (tid == 0) out[b] = red[0] + red[1] + red[2] + red[3] + b_fc2[0];
}

__global__ void cvt_k(const float* __restrict__ in, ushort_t* __restrict__ out, int n)
{
  int i = (blockIdx.x * blockDim.x + threadIdx.x) * 4;
  const int stride = gridDim.x * blockDim.x * 4;
  for (; i < n; i += stride) {
    f32x4 v = *(const f32x4*)(in + i);
    u16x4 o; o[0] = f2bf(v[0]); o[1] = f2bf(v[1]); o[2] = f2bf(v[2]); o[3] = f2bf(v[3]);
    *(u16x4*)(out + i) = o;
  }
}

extern "C" void kernel_launch(void* const* d_in, const int* in_sizes, int n_in,
                              void* d_out, int out_size, void* d_ws, size_t ws_size,
                              hipStream_t stream)
{
  const float* h       = (const float*)d_in[0];
  const float* y_seq   = (const float*)d_in[1];
  const float* W_attn1 = (const float*)d_in[2];
  const float* b_attn1 = (const float*)d_in[3];
  const float* W_attn2 = (const float*)d_in[4];
  const float* b_attn2 = (const float*)d_in[5];
  const float* W_attn3 = (const float*)d_in[6];
  // d_in[7] = b_attn3: softmax shift-invariant, unused
  const float* W_ih    = (const float*)d_in[8];
  const float* W_hh    = (const float*)d_in[9];
  const float* b_ih    = (const float*)d_in[10];
  const float* b_hh    = (const float*)d_in[11];
  const float* W_tilde = (const float*)d_in[12];
  const float* b_tilde = (const float*)d_in[13];
  const float* W_fc1   = (const float*)d_in[14];
  const float* b_fc1   = (const float*)d_in[15];
  const float* W_fc2   = (const float*)d_in[16];
  const float* b_fc2   = (const float*)d_in[17];
  (void)in_sizes; (void)n_in; (void)out_size; (void)ws_size;

  char* ws = (char*)d_ws;
  ushort_t* z2bf   = (ushort_t*)(ws + 0);          // 33554432
  ushort_t* wa1bf  = (ushort_t*)(ws + 33554432);   //  4194304
  ushort_t* whhbf  = (ushort_t*)(ws + 37748736);   //  8388608
  ushort_t* z1p0   = (ushort_t*)(ws + 46137344);   //   524288 (bf16)
  ushort_t* z1p1   = (ushort_t*)(ws + 47185920);   //   524288 (bf16)
  ushort_t* gatesp = (ushort_t*)(ws + 48234496);   //  2097152 (bf16)
  ushort_t* dsbf   = (ushort_t*)(ws + 52428800);   //  1048576
  float*    htwp   = (float*)   (ws + 54525952);   //    65536
  float*    betap  = (float*)   (ws + 54591488);   //    65536
  ushort_t* dctp   = (ushort_t*)(ws + 54657024);   //  1048576
  float*    statep = (float*)   (ws + 55705600);   //  1048576
  unsigned* bars   = (unsigned*)(ws + 56754176);   //   262144: 128 insts x 512 u32

  hipMemsetAsync(dsbf, 0, 1048576, stream);
  hipMemsetAsync(bars, 0, 262144, stream);
  cvt_k<<<dim3(256), dim3(256), 0, stream>>>(W_attn1, wa1bf, 2097152);
  cvt_k<<<dim3(256), dim3(256), 0, stream>>>(W_hh,    whhbf, 4194304);
  htw_k<<<dim3(16384), dim3(256), 0, stream>>>(h, W_tilde, htwp);
  gemm_bt_k<0><<<dim3(256, 16), dim3(256), 0, stream>>>(h, W_attn2, z2bf, b_attn1, b_attn2);

  void* kargs[] = {
    (void*)&dsbf, (void*)&wa1bf, (void*)&whhbf, (void*)&z2bf,
    (void*)&z1p0, (void*)&z1p1, (void*)&gatesp, (void*)&htwp, (void*)&W_attn3,
    (void*)&y_seq, (void*)&W_tilde, (void*)&b_tilde, (void*)&W_ih, (void*)&b_ih,
    (void*)&b_hh, (void*)&betap, (void*)&bars
  };
  hipLaunchCooperativeKernel((void*)fused_loop8_k, dim3(256), dim3(512), kargs, 0, stream);

  ct_k<<<dim3(1024), dim3(256), 0, stream>>>(h, betap, dsbf, dctp);
  gemm_bt_k<2><<<dim3(4, 16), dim3(256), 0, stream>>>(dctp, W_fc1, statep, nullptr, nullptr);
  head2_k<<<dim3(256), dim3(256), 0, stream>>>(statep, b_fc1, W_fc2, b_fc2, (float*)d_out);
}